// Round 1
// baseline (481.729 us; speedup 1.0000x reference)
//
#include <hip/hip_runtime.h>
#include <hip/hip_bf16.h>

using bf16 = __hip_bfloat16;
typedef __attribute__((ext_vector_type(8))) short short8;
typedef __attribute__((ext_vector_type(4))) float floatx4;

#define B_    16
#define TASK_ 80
#define LQ_   1024
#define D_    768
#define HH_   12
#define HD_   64
#define LIN_  4096
#define MQ_   (B_*LQ_)     // 16384 query rows
#define MF_   (B_*LIN_)    // 65536 feat rows
#define QR_   (TASK_+LQ_)  // 1104

// ---- workspace layout (bytes) ----
static constexpr size_t OFF_VAL = 0;                               // bf16 value (B,HH,LIN,HD)
static constexpr size_t OFF_FN  = OFF_VAL + (size_t)MF_*D_*2;      // bf16 fn (MF,768); reused as sampout
static constexpr size_t OFF_QN  = OFF_FN  + (size_t)MF_*D_*2;      // bf16 qn (MQ,768)
static constexpr size_t OFF_OA  = OFF_QN  + (size_t)MQ_*D_*2;      // f32 off+attw (MQ,144)
static constexpr size_t OFF_WVT = OFF_OA  + (size_t)MQ_*144*4;     // bf16 W_val^T (768,768)
static constexpr size_t OFF_WOT = OFF_WVT + (size_t)D_*D_*2;       // bf16 W_out^T (768,768)
static constexpr size_t OFF_WCT = OFF_WOT + (size_t)D_*D_*2;       // bf16 Wcat^T (256,768)

__device__ __forceinline__ void async16(const void* g, void* l) {
  __builtin_amdgcn_global_load_lds((const __attribute__((address_space(1))) void*)g,
                                   (__attribute__((address_space(3))) void*)l, 16, 0, 0);
}

// W (768 x N) f32 row-major -> WT (N x 768) bf16 row-major; N=768 here
__global__ __launch_bounds__(256) void k_transpose(const float* __restrict__ W, bf16* __restrict__ WT) {
  int idx = blockIdx.x*256 + threadIdx.x;      // over 768*768, exact
  int n = idx / D_, k = idx - n*D_;
  WT[idx] = __float2bfloat16(W[(size_t)k*D_ + n]);
}

// build Wcat^T (256 x 768): rows 0..95 = W_off cols, 96..143 = W_attw cols, rest 0
__global__ __launch_bounds__(256) void k_wcat(const float* __restrict__ Woff, const float* __restrict__ Wat,
                                              bf16* __restrict__ WT) {
  int idx = blockIdx.x*256 + threadIdx.x;      // over 256*768, exact
  int j = idx / D_, k = idx - j*D_;
  float v = 0.f;
  if (j < 96)       v = Woff[(size_t)k*96 + j];
  else if (j < 144) v = Wat[(size_t)k*48 + (j-96)];
  WT[idx] = __float2bfloat16(v);
}

// LayerNorm one row per block (row length 768), output bf16
__global__ __launch_bounds__(256) void k_ln(const float* __restrict__ x, const float* __restrict__ w,
                                            const float* __restrict__ bia, bf16* __restrict__ out,
                                            int rows_per_batch, int batch_stride, int row_off) {
  int row = blockIdx.x;
  int bat = row / rows_per_batch, r = row - bat*rows_per_batch;
  const float* src = x + (size_t)bat*batch_stride + (size_t)(row_off + r)*D_;
  int t = threadIdx.x;
  float v0 = src[t], v1 = src[t+256], v2 = src[t+512];
  float s = v0+v1+v2, s2 = v0*v0+v1*v1+v2*v2;
  #pragma unroll
  for (int o=32;o>0;o>>=1){ s += __shfl_down(s,o); s2 += __shfl_down(s2,o); }
  __shared__ float rs[4], rq[4];
  int wid = t>>6, ln = t&63;
  if (ln==0){ rs[wid]=s; rq[wid]=s2; }
  __syncthreads();
  s  = rs[0]+rs[1]+rs[2]+rs[3];
  s2 = rq[0]+rq[1]+rq[2]+rq[3];
  float mu  = s*(1.f/D_);
  float var = s2*(1.f/D_) - mu*mu;
  float rstd = rsqrtf(var + 1e-6f);
  bf16* dst = out + (size_t)row*D_;
  dst[t]     = __float2bfloat16((v0-mu)*rstd*w[t]     + bia[t]);
  dst[t+256] = __float2bfloat16((v1-mu)*rstd*w[t+256] + bia[t+256]);
  dst[t+512] = __float2bfloat16((v2-mu)*rstd*w[t+512] + bia[t+512]);
}

// 128x128 tile bf16 MFMA GEMM, A (M,K) row-major, BT (N,K) row-major, K%32==0.
// MODE 0: value proj -> bf16 scatter to (b,h,pix,hd), bias0=b_val
// MODE 1: off/attw   -> f32 (m,144) for gn<144, bias0=b_off, bias1=b_attw
// MODE 2: out proj   -> d_out f32 = query + gamma*(acc+b_out) at row b*1104+80+lq
template<int MODE>
__global__ __launch_bounds__(256) void k_gemm(const bf16* __restrict__ A, const bf16* __restrict__ BT,
                                              int K,
                                              const float* __restrict__ bias0, const float* __restrict__ bias1,
                                              void* __restrict__ outp,
                                              const float* __restrict__ query, const float* __restrict__ gamma) {
  __shared__ char lds[16384];
  char* ldsA = lds; char* ldsB = lds + 8192;
  const int tid = threadIdx.x, wid = tid>>6, lane = tid&63;
  const int bm = blockIdx.x*128, bn = blockIdx.y*128;
  const int wr = wid>>1, wc = wid&1;
  const int c0 = wid*2, c1 = c0+1;
  const int sr0 = c0*16 + (lane>>2), sr1 = sr0+16;
  const int skb = (lane&3)*8;
  const bf16* ga0 = A  + (size_t)(bm+sr0)*K + skb;
  const bf16* ga1 = A  + (size_t)(bm+sr1)*K + skb;
  const bf16* gb0 = BT + (size_t)(bn+sr0)*K + skb;
  const bf16* gb1 = BT + (size_t)(bn+sr1)*K + skb;
  char* la0 = ldsA + c0*1024; char* la1 = ldsA + c1*1024;
  char* lb0 = ldsB + c0*1024; char* lb1 = ldsB + c1*1024;
  floatx4 acc[4][4] = {};
  const int rb = (lane&15)*64 + (lane>>4)*16;   // byte offset inside a 16-row fragment read
  for (int k0 = 0; k0 < K; k0 += 32) {
    async16(ga0 + k0, la0);
    async16(ga1 + k0, la1);
    async16(gb0 + k0, lb0);
    async16(gb1 + k0, lb1);
    __syncthreads();   // drains vmcnt before barrier
    short8 af[4], bfr[4];
    #pragma unroll
    for (int i=0;i<4;++i) {
      af[i]  = *(const short8*)(ldsA + (wr*64 + i*16)*64 + rb);
      bfr[i] = *(const short8*)(ldsB + (wc*64 + i*16)*64 + rb);
    }
    #pragma unroll
    for (int mi=0;mi<4;++mi)
      #pragma unroll
      for (int ni=0;ni<4;++ni)
        acc[mi][ni] = __builtin_amdgcn_mfma_f32_16x16x32_bf16(af[mi], bfr[ni], acc[mi][ni], 0, 0, 0);
    __syncthreads();
  }
  const int rowb = (lane>>4)*4, col = lane&15;
  #pragma unroll
  for (int mi=0;mi<4;++mi) {
    #pragma unroll
    for (int ni=0;ni<4;++ni) {
      const int gn = bn + wc*64 + ni*16 + col;
      #pragma unroll
      for (int r=0;r<4;++r) {
        const int gm = bm + wr*64 + mi*16 + rowb + r;
        float v = acc[mi][ni][r];
        if constexpr (MODE==0) {
          v += bias0[gn];
          int b = gm >> 12, pix = gm & 4095;
          int h = gn >> 6,  hd  = gn & 63;
          ((bf16*)outp)[(((size_t)(b*HH_+h)*LIN_ + pix)<<6) + hd] = __float2bfloat16(v);
        } else if constexpr (MODE==1) {
          if (gn < 144) {
            v += (gn < 96) ? bias0[gn] : bias1[gn-96];
            ((float*)outp)[(size_t)gm*144 + gn] = v;
          }
        } else {
          v += bias0[gn];
          int b = gm >> 10, lq = gm & 1023;
          size_t idx = ((size_t)b*QR_ + TASK_ + lq)*D_ + gn;
          ((float*)outp)[idx] = query[idx] + gamma[gn]*v;
        }
      }
    }
  }
}

// bilinear sampling + attention-weight combine.
// one 64-lane group per (b,q,h); lane = hd channel. 4 groups per block.
__global__ __launch_bounds__(256) void k_sample(const float* __restrict__ oa_all, const float* __restrict__ refp,
                                                const bf16* __restrict__ value, bf16* __restrict__ sampout) {
  int g  = blockIdx.x*4 + (threadIdx.x>>6);   // (b*1024+q)*12 + h
  int hd = threadIdx.x & 63;
  int h = g % HH_, m = g / HH_;
  int b = m >> 10;
  const float* oa = oa_all + (size_t)m*144;
  float l0 = oa[96+h*4+0], l1 = oa[96+h*4+1], l2 = oa[96+h*4+2], l3 = oa[96+h*4+3];
  float mx = fmaxf(fmaxf(l0,l1), fmaxf(l2,l3));
  float e0 = expf(l0-mx), e1 = expf(l1-mx), e2 = expf(l2-mx), e3 = expf(l3-mx);
  float inv = 1.f/(e0+e1+e2+e3);
  float aw[4] = {e0*inv, e1*inv, e2*inv, e3*inv};
  float rx = refp[(size_t)m*2+0]*64.f - 0.5f;
  float ry = refp[(size_t)m*2+1]*64.f - 0.5f;
  const bf16* vb = value + (size_t)(b*HH_+h)*LIN_*HD_ + hd;
  float acc = 0.f;
  #pragma unroll
  for (int p=0;p<4;++p) {
    float x = rx + oa[h*8+p*2+0];   // = (ref + off/64)*64 - 0.5
    float y = ry + oa[h*8+p*2+1];
    float x0f = floorf(x), y0f = floorf(y);
    int ix = (int)x0f, iy = (int)y0f;
    float fx = x - x0f, fy = y - y0f;
    float wx0 = 1.f-fx, wy0 = 1.f-fy;
    float wcr[4] = { wx0*wy0, fx*wy0, wx0*fy, fx*fy };
    #pragma unroll
    for (int c=0;c<4;++c) {
      int xc = ix + (c&1), yc = iy + (c>>1);
      if ((unsigned)xc < 64u && (unsigned)yc < 64u) {
        acc += aw[p]*wcr[c]*__bfloat162float(vb[(size_t)((yc<<6)+xc)<<6]);
      }
    }
  }
  sampout[(size_t)m*D_ + h*64 + hd] = __float2bfloat16(acc);
}

// copy the task tokens (first 80 rows per batch) straight through
__global__ __launch_bounds__(256) void k_copytt(const float* __restrict__ query, float* __restrict__ out) {
  int idx = blockIdx.x*256 + threadIdx.x;      // 245760 float4, exact
  const int perb = TASK_*D_/4;                 // 15360
  int b = idx / perb, r = idx - b*perb;
  const float4* s = (const float4*)(query + (size_t)b*QR_*D_) + r;
  float4* d = (float4*)(out + (size_t)b*QR_*D_) + r;
  *d = *s;
}

extern "C" void kernel_launch(void* const* d_in, const int* in_sizes, int n_in,
                              void* d_out, int out_size, void* d_ws, size_t ws_size,
                              hipStream_t stream) {
  (void)in_sizes; (void)n_in; (void)out_size; (void)ws_size;
  const float* query = (const float*)d_in[0];
  const float* refp  = (const float*)d_in[1];
  const float* feat  = (const float*)d_in[2];
  const float* qn_w  = (const float*)d_in[5];
  const float* qn_b  = (const float*)d_in[6];
  const float* fn_w  = (const float*)d_in[7];
  const float* fn_b  = (const float*)d_in[8];
  const float* gamma = (const float*)d_in[9];
  const float* W_off = (const float*)d_in[10];
  const float* b_off = (const float*)d_in[11];
  const float* W_attw= (const float*)d_in[12];
  const float* b_attw= (const float*)d_in[13];
  const float* W_val = (const float*)d_in[14];
  const float* b_val = (const float*)d_in[15];
  const float* W_out = (const float*)d_in[16];
  const float* b_out = (const float*)d_in[17];
  char*  ws  = (char*)d_ws;
  float* out = (float*)d_out;

  bf16*  wsVal  = (bf16*)(ws + OFF_VAL);
  bf16*  wsFn   = (bf16*)(ws + OFF_FN);
  bf16*  wsQn   = (bf16*)(ws + OFF_QN);
  float* wsOA   = (float*)(ws + OFF_OA);
  bf16*  wsWvT  = (bf16*)(ws + OFF_WVT);
  bf16*  wsWoT  = (bf16*)(ws + OFF_WOT);
  bf16*  wsWcT  = (bf16*)(ws + OFF_WCT);
  bf16*  wsSamp = wsFn;   // fn is dead after the value GEMM

  k_transpose<<<2304, 256, 0, stream>>>(W_val, wsWvT);
  k_transpose<<<2304, 256, 0, stream>>>(W_out, wsWoT);
  k_wcat<<<768, 256, 0, stream>>>(W_off, W_attw, wsWcT);
  k_ln<<<MQ_, 256, 0, stream>>>(query, qn_w, qn_b, wsQn, LQ_, QR_*D_, TASK_);
  k_ln<<<MF_, 256, 0, stream>>>(feat, fn_w, fn_b, wsFn, LIN_, LIN_*D_, 0);
  k_gemm<1><<<dim3(MQ_/128, 2), 256, 0, stream>>>(wsQn, wsWcT, D_, b_off, b_attw, wsOA, nullptr, nullptr);
  k_gemm<0><<<dim3(MF_/128, 6), 256, 0, stream>>>(wsFn, wsWvT, D_, b_val, nullptr, wsVal, nullptr, nullptr);
  k_sample<<<(MQ_*HH_)/4, 256, 0, stream>>>(wsOA, refp, wsVal, wsSamp);
  k_gemm<2><<<dim3(MQ_/128, 6), 256, 0, stream>>>(wsSamp, wsWoT, D_, b_out, nullptr, out, query, gamma);
  k_copytt<<<(B_*TASK_*D_/4)/256, 256, 0, stream>>>(query, out);
}

// Round 2
// 405.826 us; speedup vs baseline: 1.1870x; 1.1870x over previous
//
#include <hip/hip_runtime.h>
#include <hip/hip_bf16.h>

using bf16 = __hip_bfloat16;
typedef __attribute__((ext_vector_type(8))) short short8;
typedef __attribute__((ext_vector_type(4))) short short4v;
typedef __attribute__((ext_vector_type(4))) float floatx4;

#define B_    16
#define TASK_ 80
#define LQ_   1024
#define D_    768
#define HH_   12
#define HD_   64
#define LIN_  4096
#define MQ_   (B_*LQ_)     // 16384 query rows
#define MF_   (B_*LIN_)    // 65536 feat rows
#define QR_   (TASK_+LQ_)  // 1104

// ---- workspace layout (bytes) ----
static constexpr size_t OFF_VAL = 0;                               // bf16 value (B,HH,LIN,HD)
static constexpr size_t OFF_FN  = OFF_VAL + (size_t)MF_*D_*2;      // bf16 fn (MF,768); reused as sampout
static constexpr size_t OFF_QN  = OFF_FN  + (size_t)MF_*D_*2;      // bf16 qn (MQ,768); reused as prep
static constexpr size_t OFF_OA  = OFF_QN  + (size_t)MQ_*D_*2;      // f32 off+attw (MQ,144)
static constexpr size_t OFF_WVT = OFF_OA  + (size_t)MQ_*144*4;     // bf16 W_val^T (768,768)
static constexpr size_t OFF_WOT = OFF_WVT + (size_t)D_*D_*2;       // bf16 W_out^T (768,768)
static constexpr size_t OFF_WCT = OFF_WOT + (size_t)D_*D_*2;       // bf16 Wcat^T (256,768)

__device__ __forceinline__ void async16(const void* g, void* l) {
  __builtin_amdgcn_global_load_lds((const __attribute__((address_space(1))) void*)g,
                                   (__attribute__((address_space(3))) void*)l, 16, 0, 0);
}

// LDS-tiled transpose: W (768x768) f32 row-major -> WT = W^T bf16 row-major
__global__ __launch_bounds__(256) void k_transpose(const float* __restrict__ W, bf16* __restrict__ WT) {
  __shared__ float t[64][65];
  int bx = blockIdx.x % 12, by = blockIdx.x / 12;
  int n0 = bx*64, k0 = by*64;
  int col = threadIdx.x & 63, rg = threadIdx.x >> 6;
  #pragma unroll
  for (int i=0;i<16;++i) { int row = i*4+rg; t[row][col] = W[(size_t)(k0+row)*D_ + n0+col]; }
  __syncthreads();
  #pragma unroll
  for (int i=0;i<16;++i) { int row = i*4+rg; WT[(size_t)(n0+row)*D_ + k0+col] = __float2bfloat16(t[col][row]); }
}

// build Wcat^T (256 x 768): rows 0..95 = W_off cols, 96..143 = W_attw cols, rest 0
__global__ __launch_bounds__(256) void k_wcat(const float* __restrict__ Woff, const float* __restrict__ Wat,
                                              bf16* __restrict__ WT) {
  int idx = blockIdx.x*256 + threadIdx.x;      // over 256*768, exact
  int j = idx / D_, k = idx - j*D_;
  float v = 0.f;
  if (j < 96)       v = Woff[(size_t)k*96 + j];
  else if (j < 144) v = Wat[(size_t)k*48 + (j-96)];
  WT[idx] = __float2bfloat16(v);
}

// LayerNorm one row per block (row length 768), output bf16
__global__ __launch_bounds__(256) void k_ln(const float* __restrict__ x, const float* __restrict__ w,
                                            const float* __restrict__ bia, bf16* __restrict__ out,
                                            int rows_per_batch, int batch_stride, int row_off) {
  int row = blockIdx.x;
  int bat = row / rows_per_batch, r = row - bat*rows_per_batch;
  const float* src = x + (size_t)bat*batch_stride + (size_t)(row_off + r)*D_;
  int t = threadIdx.x;
  float v0 = src[t], v1 = src[t+256], v2 = src[t+512];
  float s = v0+v1+v2, s2 = v0*v0+v1*v1+v2*v2;
  #pragma unroll
  for (int o=32;o>0;o>>=1){ s += __shfl_down(s,o); s2 += __shfl_down(s2,o); }
  __shared__ float rs[4], rq[4];
  int wid = t>>6, ln = t&63;
  if (ln==0){ rs[wid]=s; rq[wid]=s2; }
  __syncthreads();
  s  = rs[0]+rs[1]+rs[2]+rs[3];
  s2 = rq[0]+rq[1]+rq[2]+rq[3];
  float mu  = s*(1.f/D_);
  float var = s2*(1.f/D_) - mu*mu;
  float rstd = rsqrtf(var + 1e-6f);
  bf16* dst = out + (size_t)row*D_;
  dst[t]     = __float2bfloat16((v0-mu)*rstd*w[t]     + bia[t]);
  dst[t+256] = __float2bfloat16((v1-mu)*rstd*w[t+256] + bia[t+256]);
  dst[t+512] = __float2bfloat16((v2-mu)*rstd*w[t+512] + bia[t+512]);
}

// 128x128 tile bf16 MFMA GEMM, A (M,K) row-major, BT (N,K) row-major, K%32==0.
template<int MODE>
__global__ __launch_bounds__(256) void k_gemm(const bf16* __restrict__ A, const bf16* __restrict__ BT,
                                              int K,
                                              const float* __restrict__ bias0, const float* __restrict__ bias1,
                                              void* __restrict__ outp,
                                              const float* __restrict__ query, const float* __restrict__ gamma) {
  __shared__ char lds[16384];
  char* ldsA = lds; char* ldsB = lds + 8192;
  const int tid = threadIdx.x, wid = tid>>6, lane = tid&63;
  const int bm = blockIdx.x*128, bn = blockIdx.y*128;
  const int wr = wid>>1, wc = wid&1;
  const int c0 = wid*2, c1 = c0+1;
  const int sr0 = c0*16 + (lane>>2), sr1 = sr0+16;
  const int skb = (lane&3)*8;
  const bf16* ga0 = A  + (size_t)(bm+sr0)*K + skb;
  const bf16* ga1 = A  + (size_t)(bm+sr1)*K + skb;
  const bf16* gb0 = BT + (size_t)(bn+sr0)*K + skb;
  const bf16* gb1 = BT + (size_t)(bn+sr1)*K + skb;
  char* la0 = ldsA + c0*1024; char* la1 = ldsA + c1*1024;
  char* lb0 = ldsB + c0*1024; char* lb1 = ldsB + c1*1024;
  floatx4 acc[4][4] = {};
  const int rb = (lane&15)*64 + (lane>>4)*16;
  for (int k0 = 0; k0 < K; k0 += 32) {
    async16(ga0 + k0, la0);
    async16(ga1 + k0, la1);
    async16(gb0 + k0, lb0);
    async16(gb1 + k0, lb1);
    __syncthreads();
    short8 af[4], bfr[4];
    #pragma unroll
    for (int i=0;i<4;++i) {
      af[i]  = *(const short8*)(ldsA + (wr*64 + i*16)*64 + rb);
      bfr[i] = *(const short8*)(ldsB + (wc*64 + i*16)*64 + rb);
    }
    #pragma unroll
    for (int mi=0;mi<4;++mi)
      #pragma unroll
      for (int ni=0;ni<4;++ni)
        acc[mi][ni] = __builtin_amdgcn_mfma_f32_16x16x32_bf16(af[mi], bfr[ni], acc[mi][ni], 0, 0, 0);
    __syncthreads();
  }
  const int rowb = (lane>>4)*4, col = lane&15;
  #pragma unroll
  for (int mi=0;mi<4;++mi) {
    #pragma unroll
    for (int ni=0;ni<4;++ni) {
      const int gn = bn + wc*64 + ni*16 + col;
      #pragma unroll
      for (int r=0;r<4;++r) {
        const int gm = bm + wr*64 + mi*16 + rowb + r;
        float v = acc[mi][ni][r];
        if constexpr (MODE==0) {
          v += bias0[gn];
          int b = gm >> 12, pix = gm & 4095;
          int h = gn >> 6,  hd  = gn & 63;
          ((bf16*)outp)[(((size_t)(b*HH_+h)*LIN_ + pix)<<6) + hd] = __float2bfloat16(v);
        } else if constexpr (MODE==1) {
          if (gn < 144) {
            v += (gn < 96) ? bias0[gn] : bias1[gn-96];
            ((float*)outp)[(size_t)gm*144 + gn] = v;
          }
        } else {
          v += bias0[gn];
          int b = gm >> 10, lq = gm & 1023;
          size_t idx = ((size_t)b*QR_ + TASK_ + lq)*D_ + gn;
          ((float*)outp)[idx] = query[idx] + gamma[gn]*v;
        }
      }
    }
  }
}

// precompute per (m,h,p): 4 corners x {combined weight, clamped pixel index}
__global__ __launch_bounds__(256) void k_prep(const float* __restrict__ oa_all,
                                              const float* __restrict__ refp,
                                              float2* __restrict__ prep) {
  int idx = blockIdx.x*256 + threadIdx.x;     // MQ_*HH_*4 = 786432, exact
  int p = idx & 3, mh = idx >> 2;
  int h = mh % HH_, m = mh / HH_;
  const float* oa = oa_all + (size_t)m*144;
  float l0 = oa[96+h*4+0], l1 = oa[96+h*4+1], l2 = oa[96+h*4+2], l3 = oa[96+h*4+3];
  float mx = fmaxf(fmaxf(l0,l1), fmaxf(l2,l3));
  float e0 = expf(l0-mx), e1 = expf(l1-mx), e2 = expf(l2-mx), e3 = expf(l3-mx);
  float inv = 1.f/(e0+e1+e2+e3);
  float ep = (p==0)?e0:(p==1)?e1:(p==2)?e2:e3;
  float awp = ep*inv;
  float x = refp[(size_t)m*2+0]*64.f - 0.5f + oa[h*8+p*2+0];
  float y = refp[(size_t)m*2+1]*64.f - 0.5f + oa[h*8+p*2+1];
  float x0f = floorf(x), y0f = floorf(y);
  int ix = (int)x0f, iy = (int)y0f;
  float fx = x-x0f, fy = y-y0f;
  float wx[2] = {1.f-fx, fx}, wy[2] = {1.f-fy, fy};
  float2 e[4];
  #pragma unroll
  for (int c=0;c<4;++c) {
    int dx = c&1, dy = c>>1;
    int xc = ix+dx, yc = iy+dy;
    bool valid = ((unsigned)xc < 64u) && ((unsigned)yc < 64u);
    float w = valid ? awp*wx[dx]*wy[dy] : 0.f;
    int xi = min(max(xc,0),63), yi = min(max(yc,0),63);
    e[c].x = w;
    e[c].y = __int_as_float(yi*64+xi);
  }
  float2* dst = prep + (size_t)mh*16 + p*4;
  *(float4*)(dst)   = make_float4(e[0].x, e[0].y, e[1].x, e[1].y);
  *(float4*)(dst+2) = make_float4(e[2].x, e[2].y, e[3].x, e[3].y);
}

// gather+combine: wave = one (m,h) group; lane = (channel_quad<<2) | point
__global__ __launch_bounds__(256) void k_sample(const float2* __restrict__ prep,
                                                const bf16* __restrict__ value,
                                                bf16* __restrict__ sampout) {
  int g  = blockIdx.x*4 + (threadIdx.x>>6);   // (b*1024+q)*12 + h
  int lane = threadIdx.x & 63;
  int cq = lane >> 2, p = lane & 3;
  int h = g % HH_, m = g / HH_;
  int b = m >> 10;
  const float2* pb = prep + (size_t)g*16 + p*4;
  float4 e01 = *(const float4*)(pb);
  float4 e23 = *(const float4*)(pb+2);
  const bf16* vb = value + (((size_t)(b*HH_+h))<<18) + (cq<<2);   // LIN_*HD_ = 262144
  float a0=0.f, a1=0.f, a2=0.f, a3=0.f;
  float wv[4]  = {e01.x, e01.z, e23.x, e23.z};
  int   pix[4] = {__float_as_int(e01.y), __float_as_int(e01.w),
                  __float_as_int(e23.y), __float_as_int(e23.w)};
  #pragma unroll
  for (int c=0;c<4;++c) {
    short4v v = *(const short4v*)(vb + ((size_t)pix[c]<<6));
    float w = wv[c];
    a0 += w*__uint_as_float(((unsigned)(unsigned short)v[0])<<16);
    a1 += w*__uint_as_float(((unsigned)(unsigned short)v[1])<<16);
    a2 += w*__uint_as_float(((unsigned)(unsigned short)v[2])<<16);
    a3 += w*__uint_as_float(((unsigned)(unsigned short)v[3])<<16);
  }
  // reduce over the 4 points (lane quads)
  a0 += __shfl_xor(a0,1); a0 += __shfl_xor(a0,2);
  a1 += __shfl_xor(a1,1); a1 += __shfl_xor(a1,2);
  a2 += __shfl_xor(a2,1); a2 += __shfl_xor(a2,2);
  a3 += __shfl_xor(a3,1); a3 += __shfl_xor(a3,2);
  if (p == 0) {
    short4v o;
    o[0] = (short)__bfloat16_as_ushort(__float2bfloat16(a0));
    o[1] = (short)__bfloat16_as_ushort(__float2bfloat16(a1));
    o[2] = (short)__bfloat16_as_ushort(__float2bfloat16(a2));
    o[3] = (short)__bfloat16_as_ushort(__float2bfloat16(a3));
    *(short4v*)(sampout + (size_t)m*D_ + h*64 + cq*4) = o;
  }
}

// copy the task tokens (first 80 rows per batch) straight through
__global__ __launch_bounds__(256) void k_copytt(const float* __restrict__ query, float* __restrict__ out) {
  int idx = blockIdx.x*256 + threadIdx.x;      // 245760/4 float4, exact
  const int perb = TASK_*D_/4;                 // 15360
  int b = idx / perb, r = idx - b*perb;
  const float4* s = (const float4*)(query + (size_t)b*QR_*D_) + r;
  float4* d = (float4*)(out + (size_t)b*QR_*D_) + r;
  *d = *s;
}

extern "C" void kernel_launch(void* const* d_in, const int* in_sizes, int n_in,
                              void* d_out, int out_size, void* d_ws, size_t ws_size,
                              hipStream_t stream) {
  (void)in_sizes; (void)n_in; (void)out_size; (void)ws_size;
  const float* query = (const float*)d_in[0];
  const float* refp  = (const float*)d_in[1];
  const float* feat  = (const float*)d_in[2];
  const float* qn_w  = (const float*)d_in[5];
  const float* qn_b  = (const float*)d_in[6];
  const float* fn_w  = (const float*)d_in[7];
  const float* fn_b  = (const float*)d_in[8];
  const float* gamma = (const float*)d_in[9];
  const float* W_off = (const float*)d_in[10];
  const float* b_off = (const float*)d_in[11];
  const float* W_attw= (const float*)d_in[12];
  const float* b_attw= (const float*)d_in[13];
  const float* W_val = (const float*)d_in[14];
  const float* b_val = (const float*)d_in[15];
  const float* W_out = (const float*)d_in[16];
  const float* b_out = (const float*)d_in[17];
  char*  ws  = (char*)d_ws;
  float* out = (float*)d_out;

  bf16*   wsVal  = (bf16*)(ws + OFF_VAL);
  bf16*   wsFn   = (bf16*)(ws + OFF_FN);
  bf16*   wsQn   = (bf16*)(ws + OFF_QN);
  float*  wsOA   = (float*)(ws + OFF_OA);
  bf16*   wsWvT  = (bf16*)(ws + OFF_WVT);
  bf16*   wsWoT  = (bf16*)(ws + OFF_WOT);
  bf16*   wsWcT  = (bf16*)(ws + OFF_WCT);
  float2* wsPrep = (float2*)(ws + OFF_QN);   // qn dead after MODE-1 GEMM; same 25.17 MB
  bf16*   wsSamp = wsFn;                     // fn dead after value GEMM

  k_transpose<<<144, 256, 0, stream>>>(W_val, wsWvT);
  k_transpose<<<144, 256, 0, stream>>>(W_out, wsWoT);
  k_wcat<<<768, 256, 0, stream>>>(W_off, W_attw, wsWcT);
  k_ln<<<MQ_, 256, 0, stream>>>(query, qn_w, qn_b, wsQn, LQ_, QR_*D_, TASK_);
  k_ln<<<MF_, 256, 0, stream>>>(feat, fn_w, fn_b, wsFn, LIN_, LIN_*D_, 0);
  k_gemm<1><<<dim3(MQ_/128, 2), 256, 0, stream>>>(wsQn, wsWcT, D_, b_off, b_attw, wsOA, nullptr, nullptr);
  k_prep<<<(MQ_*HH_*4)/256, 256, 0, stream>>>(wsOA, refp, wsPrep);
  k_gemm<0><<<dim3(MF_/128, 6), 256, 0, stream>>>(wsFn, wsWvT, D_, b_val, nullptr, wsVal, nullptr, nullptr);
  k_sample<<<(MQ_*HH_)/4, 256, 0, stream>>>(wsPrep, wsVal, wsSamp);
  k_gemm<2><<<dim3(MQ_/128, 6), 256, 0, stream>>>(wsSamp, wsWoT, D_, b_out, nullptr, out, query, gamma);
  k_copytt<<<(B_*TASK_*D_/4)/256, 256, 0, stream>>>(query, out);
}

// Round 3
// 382.903 us; speedup vs baseline: 1.2581x; 1.0599x over previous
//
#include <hip/hip_runtime.h>
#include <hip/hip_bf16.h>

using bf16 = __hip_bfloat16;
typedef __attribute__((ext_vector_type(8))) short short8;
typedef __attribute__((ext_vector_type(4))) short short4v;
typedef __attribute__((ext_vector_type(4))) float floatx4;

#define B_    16
#define TASK_ 80
#define LQ_   1024
#define D_    768
#define HH_   12
#define HD_   64
#define LIN_  4096
#define MQ_   (B_*LQ_)     // 16384 query rows
#define MF_   (B_*LIN_)    // 65536 feat rows
#define QR_   (TASK_+LQ_)  // 1104

// ---- workspace layout (bytes) ----
static constexpr size_t OFF_VAL = 0;                               // bf16 value (B,HH,LIN,HD)
static constexpr size_t OFF_FN  = OFF_VAL + (size_t)MF_*D_*2;      // bf16 fn (MF,768); reused as sampout
static constexpr size_t OFF_QN  = OFF_FN  + (size_t)MF_*D_*2;      // bf16 qn (MQ,768); reused as prep
static constexpr size_t OFF_OA  = OFF_QN  + (size_t)MQ_*D_*2;      // f32 off+attw (MQ,144)
static constexpr size_t OFF_WVT = OFF_OA  + (size_t)MQ_*144*4;     // bf16 W_val^T (768,768)
static constexpr size_t OFF_WOT = OFF_WVT + (size_t)D_*D_*2;       // bf16 W_out^T (768,768)
static constexpr size_t OFF_WCT = OFF_WOT + (size_t)D_*D_*2;       // bf16 Wcat^T (256,768)

__device__ __forceinline__ void async16(const void* g, void* l) {
  __builtin_amdgcn_global_load_lds((const __attribute__((address_space(1))) void*)g,
                                   (__attribute__((address_space(3))) void*)l, 16, 0, 0);
}

// LDS-tiled transpose: W (768x768) f32 row-major -> WT = W^T bf16 row-major
__global__ __launch_bounds__(256) void k_transpose(const float* __restrict__ W, bf16* __restrict__ WT) {
  __shared__ float t[64][65];
  int bx = blockIdx.x % 12, by = blockIdx.x / 12;
  int n0 = bx*64, k0 = by*64;
  int col = threadIdx.x & 63, rg = threadIdx.x >> 6;
  #pragma unroll
  for (int i=0;i<16;++i) { int row = i*4+rg; t[row][col] = W[(size_t)(k0+row)*D_ + n0+col]; }
  __syncthreads();
  #pragma unroll
  for (int i=0;i<16;++i) { int row = i*4+rg; WT[(size_t)(n0+row)*D_ + k0+col] = __float2bfloat16(t[col][row]); }
}

// build Wcat^T (256 x 768): rows 0..95 = W_off cols, 96..143 = W_attw cols, rest 0
__global__ __launch_bounds__(256) void k_wcat(const float* __restrict__ Woff, const float* __restrict__ Wat,
                                              bf16* __restrict__ WT) {
  int idx = blockIdx.x*256 + threadIdx.x;      // over 256*768, exact
  int j = idx / D_, k = idx - j*D_;
  float v = 0.f;
  if (j < 96)       v = Woff[(size_t)k*96 + j];
  else if (j < 144) v = Wat[(size_t)k*48 + (j-96)];
  WT[idx] = __float2bfloat16(v);
}

// LayerNorm one row per block (row length 768), output bf16
__global__ __launch_bounds__(256) void k_ln(const float* __restrict__ x, const float* __restrict__ w,
                                            const float* __restrict__ bia, bf16* __restrict__ out,
                                            int rows_per_batch, int batch_stride, int row_off) {
  int row = blockIdx.x;
  int bat = row / rows_per_batch, r = row - bat*rows_per_batch;
  const float* src = x + (size_t)bat*batch_stride + (size_t)(row_off + r)*D_;
  int t = threadIdx.x;
  float v0 = src[t], v1 = src[t+256], v2 = src[t+512];
  float s = v0+v1+v2, s2 = v0*v0+v1*v1+v2*v2;
  #pragma unroll
  for (int o=32;o>0;o>>=1){ s += __shfl_down(s,o); s2 += __shfl_down(s2,o); }
  __shared__ float rs[4], rq[4];
  int wid = t>>6, ln = t&63;
  if (ln==0){ rs[wid]=s; rq[wid]=s2; }
  __syncthreads();
  s  = rs[0]+rs[1]+rs[2]+rs[3];
  s2 = rq[0]+rq[1]+rq[2]+rq[3];
  float mu  = s*(1.f/D_);
  float var = s2*(1.f/D_) - mu*mu;
  float rstd = rsqrtf(var + 1e-6f);
  bf16* dst = out + (size_t)row*D_;
  dst[t]     = __float2bfloat16((v0-mu)*rstd*w[t]     + bia[t]);
  dst[t+256] = __float2bfloat16((v1-mu)*rstd*w[t+256] + bia[t+256]);
  dst[t+512] = __float2bfloat16((v2-mu)*rstd*w[t+512] + bia[t+512]);
}

// 128x128 tile bf16 MFMA GEMM, A (M,K) row-major, BT (N,K) row-major, K%32==0.
// Double-buffered LDS (prefetch next K-tile before compute), XOR-swizzled
// staging source + read addr (2-way banks, conflict-free), ly-fastest block
// remap for A-panel L2 reuse.
template<int MODE>
__global__ __launch_bounds__(256) void k_gemm(const bf16* __restrict__ A, const bf16* __restrict__ BT,
                                              int K,
                                              const float* __restrict__ bias0, const float* __restrict__ bias1,
                                              void* __restrict__ outp,
                                              const float* __restrict__ query, const float* __restrict__ gamma) {
  __shared__ char lds[32768];    // 2 buffers x (A 8KB + B 8KB)
  const int tid = threadIdx.x, wid = tid>>6, lane = tid&63;
  // remap so the N-tile index runs fastest -> consecutive blocks share A panel
  const int lin = blockIdx.y*gridDim.x + blockIdx.x;
  const int ny = gridDim.y;
  const int bm = (lin/ny)*128, bn = (lin%ny)*128;
  const int wr = wid>>1, wc = wid&1;
  const int c0 = wid*2, c1 = c0+1;
  const int sr0 = c0*16 + (lane>>2), sr1 = sr0+16;
  // source-side XOR swizzle: slot (lane&3) in LDS receives global slot (lane&3)^((row>>1)&3)
  const int skb = (((lane&3) ^ ((lane>>3)&3)))*8;
  const bf16* ga0 = A  + (size_t)(bm+sr0)*K + skb;
  const bf16* ga1 = A  + (size_t)(bm+sr1)*K + skb;
  const bf16* gb0 = BT + (size_t)(bn+sr0)*K + skb;
  const bf16* gb1 = BT + (size_t)(bn+sr1)*K + skb;
  // read-side: same XOR on the 16B slot index
  const int rb = (lane&15)*64 + ((((lane>>4) ^ ((lane>>1)&3)))<<4);
  floatx4 acc[4][4] = {};
  {
    char* dA = lds; char* dB = lds + 8192;
    async16(ga0, dA + c0*1024); async16(ga1, dA + c1*1024);
    async16(gb0, dB + c0*1024); async16(gb1, dB + c1*1024);
  }
  __syncthreads();
  int cur = 0;
  for (int k0 = 0; k0 < K; k0 += 32) {
    if (k0 + 32 < K) {   // prefetch next K-tile into the other buffer
      char* dA = lds + ((cur^1)<<14); char* dB = dA + 8192;
      async16(ga0+k0+32, dA + c0*1024); async16(ga1+k0+32, dA + c1*1024);
      async16(gb0+k0+32, dB + c0*1024); async16(gb1+k0+32, dB + c1*1024);
    }
    const char* ldsA = lds + (cur<<14); const char* ldsB = ldsA + 8192;
    short8 af[4], bfr[4];
    #pragma unroll
    for (int i=0;i<4;++i) {
      af[i]  = *(const short8*)(ldsA + (wr*64 + i*16)*64 + rb);
      bfr[i] = *(const short8*)(ldsB + (wc*64 + i*16)*64 + rb);
    }
    #pragma unroll
    for (int mi=0;mi<4;++mi)
      #pragma unroll
      for (int ni=0;ni<4;++ni)
        acc[mi][ni] = __builtin_amdgcn_mfma_f32_16x16x32_bf16(af[mi], bfr[ni], acc[mi][ni], 0, 0, 0);
    __syncthreads();   // drains vmcnt (prefetch landed) + lgkmcnt; safe buffer swap
    cur ^= 1;
  }
  const int rowb = (lane>>4)*4, col = lane&15;
  #pragma unroll
  for (int mi=0;mi<4;++mi) {
    #pragma unroll
    for (int ni=0;ni<4;++ni) {
      const int gn = bn + wc*64 + ni*16 + col;
      #pragma unroll
      for (int r=0;r<4;++r) {
        const int gm = bm + wr*64 + mi*16 + rowb + r;
        float v = acc[mi][ni][r];
        if constexpr (MODE==0) {
          v += bias0[gn];
          int b = gm >> 12, pix = gm & 4095;
          int h = gn >> 6,  hd  = gn & 63;
          ((bf16*)outp)[(((size_t)(b*HH_+h)*LIN_ + pix)<<6) + hd] = __float2bfloat16(v);
        } else if constexpr (MODE==1) {
          if (gn < 144) {
            v += (gn < 96) ? bias0[gn] : bias1[gn-96];
            ((float*)outp)[(size_t)gm*144 + gn] = v;
          }
        } else {
          v += bias0[gn];
          int b = gm >> 10, lq = gm & 1023;
          size_t idx = ((size_t)b*QR_ + TASK_ + lq)*D_ + gn;
          ((float*)outp)[idx] = query[idx] + gamma[gn]*v;
        }
      }
    }
  }
}

// precompute per (m,h,p): 4 corners x {combined weight, clamped pixel index}
__global__ __launch_bounds__(256) void k_prep(const float* __restrict__ oa_all,
                                              const float* __restrict__ refp,
                                              float2* __restrict__ prep) {
  int idx = blockIdx.x*256 + threadIdx.x;     // MQ_*HH_*4 = 786432, exact
  int p = idx & 3, mh = idx >> 2;
  int h = mh % HH_, m = mh / HH_;
  const float* oa = oa_all + (size_t)m*144;
  float l0 = oa[96+h*4+0], l1 = oa[96+h*4+1], l2 = oa[96+h*4+2], l3 = oa[96+h*4+3];
  float mx = fmaxf(fmaxf(l0,l1), fmaxf(l2,l3));
  float e0 = expf(l0-mx), e1 = expf(l1-mx), e2 = expf(l2-mx), e3 = expf(l3-mx);
  float inv = 1.f/(e0+e1+e2+e3);
  float ep = (p==0)?e0:(p==1)?e1:(p==2)?e2:e3;
  float awp = ep*inv;
  float x = refp[(size_t)m*2+0]*64.f - 0.5f + oa[h*8+p*2+0];
  float y = refp[(size_t)m*2+1]*64.f - 0.5f + oa[h*8+p*2+1];
  float x0f = floorf(x), y0f = floorf(y);
  int ix = (int)x0f, iy = (int)y0f;
  float fx = x-x0f, fy = y-y0f;
  float wx[2] = {1.f-fx, fx}, wy[2] = {1.f-fy, fy};
  float2 e[4];
  #pragma unroll
  for (int c=0;c<4;++c) {
    int dx = c&1, dy = c>>1;
    int xc = ix+dx, yc = iy+dy;
    bool valid = ((unsigned)xc < 64u) && ((unsigned)yc < 64u);
    float w = valid ? awp*wx[dx]*wy[dy] : 0.f;
    int xi = min(max(xc,0),63), yi = min(max(yc,0),63);
    e[c].x = w;
    e[c].y = __int_as_float(yi*64+xi);
  }
  float2* dst = prep + (size_t)mh*16 + p*4;
  *(float4*)(dst)   = make_float4(e[0].x, e[0].y, e[1].x, e[1].y);
  *(float4*)(dst+2) = make_float4(e[2].x, e[2].y, e[3].x, e[3].y);
}

// gather+combine: wave = one (m,h) group; lane = (channel_quad<<2) | point
__global__ __launch_bounds__(256) void k_sample(const float2* __restrict__ prep,
                                                const bf16* __restrict__ value,
                                                bf16* __restrict__ sampout) {
  int g  = blockIdx.x*4 + (threadIdx.x>>6);   // (b*1024+q)*12 + h
  int lane = threadIdx.x & 63;
  int cq = lane >> 2, p = lane & 3;
  int h = g % HH_, m = g / HH_;
  int b = m >> 10;
  const float2* pb = prep + (size_t)g*16 + p*4;
  float4 e01 = *(const float4*)(pb);
  float4 e23 = *(const float4*)(pb+2);
  const bf16* vb = value + (((size_t)(b*HH_+h))<<18) + (cq<<2);   // LIN_*HD_ = 262144
  float a0=0.f, a1=0.f, a2=0.f, a3=0.f;
  float wv[4]  = {e01.x, e01.z, e23.x, e23.z};
  int   pix[4] = {__float_as_int(e01.y), __float_as_int(e01.w),
                  __float_as_int(e23.y), __float_as_int(e23.w)};
  #pragma unroll
  for (int c=0;c<4;++c) {
    short4v v = *(const short4v*)(vb + ((size_t)pix[c]<<6));
    float w = wv[c];
    a0 += w*__uint_as_float(((unsigned)(unsigned short)v[0])<<16);
    a1 += w*__uint_as_float(((unsigned)(unsigned short)v[1])<<16);
    a2 += w*__uint_as_float(((unsigned)(unsigned short)v[2])<<16);
    a3 += w*__uint_as_float(((unsigned)(unsigned short)v[3])<<16);
  }
  a0 += __shfl_xor(a0,1); a0 += __shfl_xor(a0,2);
  a1 += __shfl_xor(a1,1); a1 += __shfl_xor(a1,2);
  a2 += __shfl_xor(a2,1); a2 += __shfl_xor(a2,2);
  a3 += __shfl_xor(a3,1); a3 += __shfl_xor(a3,2);
  if (p == 0) {
    short4v o;
    o[0] = (short)__bfloat16_as_ushort(__float2bfloat16(a0));
    o[1] = (short)__bfloat16_as_ushort(__float2bfloat16(a1));
    o[2] = (short)__bfloat16_as_ushort(__float2bfloat16(a2));
    o[3] = (short)__bfloat16_as_ushort(__float2bfloat16(a3));
    *(short4v*)(sampout + (size_t)m*D_ + h*64 + cq*4) = o;
  }
}

// copy the task tokens (first 80 rows per batch) straight through
__global__ __launch_bounds__(256) void k_copytt(const float* __restrict__ query, float* __restrict__ out) {
  int idx = blockIdx.x*256 + threadIdx.x;      // 245760/4 float4, exact
  const int perb = TASK_*D_/4;                 // 15360
  int b = idx / perb, r = idx - b*perb;
  const float4* s = (const float4*)(query + (size_t)b*QR_*D_) + r;
  float4* d = (float4*)(out + (size_t)b*QR_*D_) + r;
  *d = *s;
}

extern "C" void kernel_launch(void* const* d_in, const int* in_sizes, int n_in,
                              void* d_out, int out_size, void* d_ws, size_t ws_size,
                              hipStream_t stream) {
  (void)in_sizes; (void)n_in; (void)out_size; (void)ws_size;
  const float* query = (const float*)d_in[0];
  const float* refp  = (const float*)d_in[1];
  const float* feat  = (const float*)d_in[2];
  const float* qn_w  = (const float*)d_in[5];
  const float* qn_b  = (const float*)d_in[6];
  const float* fn_w  = (const float*)d_in[7];
  const float* fn_b  = (const float*)d_in[8];
  const float* gamma = (const float*)d_in[9];
  const float* W_off = (const float*)d_in[10];
  const float* b_off = (const float*)d_in[11];
  const float* W_attw= (const float*)d_in[12];
  const float* b_attw= (const float*)d_in[13];
  const float* W_val = (const float*)d_in[14];
  const float* b_val = (const float*)d_in[15];
  const float* W_out = (const float*)d_in[16];
  const float* b_out = (const float*)d_in[17];
  char*  ws  = (char*)d_ws;
  float* out = (float*)d_out;

  bf16*   wsVal  = (bf16*)(ws + OFF_VAL);
  bf16*   wsFn   = (bf16*)(ws + OFF_FN);
  bf16*   wsQn   = (bf16*)(ws + OFF_QN);
  float*  wsOA   = (float*)(ws + OFF_OA);
  bf16*   wsWvT  = (bf16*)(ws + OFF_WVT);
  bf16*   wsWoT  = (bf16*)(ws + OFF_WOT);
  bf16*   wsWcT  = (bf16*)(ws + OFF_WCT);
  float2* wsPrep = (float2*)(ws + OFF_QN);   // qn dead after MODE-1 GEMM
  bf16*   wsSamp = wsFn;                     // fn dead after value GEMM

  k_transpose<<<144, 256, 0, stream>>>(W_val, wsWvT);
  k_transpose<<<144, 256, 0, stream>>>(W_out, wsWoT);
  k_wcat<<<768, 256, 0, stream>>>(W_off, W_attw, wsWcT);
  k_ln<<<MQ_, 256, 0, stream>>>(query, qn_w, qn_b, wsQn, LQ_, QR_*D_, TASK_);
  k_ln<<<MF_, 256, 0, stream>>>(feat, fn_w, fn_b, wsFn, LIN_, LIN_*D_, 0);
  k_gemm<1><<<dim3(MQ_/128, 2), 256, 0, stream>>>(wsQn, wsWcT, D_, b_off, b_attw, wsOA, nullptr, nullptr);
  k_prep<<<(MQ_*HH_*4)/256, 256, 0, stream>>>(wsOA, refp, wsPrep);
  k_gemm<0><<<dim3(MF_/128, 6), 256, 0, stream>>>(wsFn, wsWvT, D_, b_val, nullptr, wsVal, nullptr, nullptr);
  k_sample<<<(MQ_*HH_)/4, 256, 0, stream>>>(wsPrep, wsVal, wsSamp);
  k_gemm<2><<<dim3(MQ_/128, 6), 256, 0, stream>>>(wsSamp, wsWoT, D_, b_out, nullptr, out, query, gamma);
  k_copytt<<<(B_*TASK_*D_/4)/256, 256, 0, stream>>>(query, out);
}

// Round 4
// 365.787 us; speedup vs baseline: 1.3170x; 1.0468x over previous
//
#include <hip/hip_runtime.h>
#include <hip/hip_bf16.h>

using bf16 = __hip_bfloat16;
typedef __attribute__((ext_vector_type(8))) short short8;
typedef __attribute__((ext_vector_type(4))) short short4v;
typedef __attribute__((ext_vector_type(4))) float floatx4;

#define B_    16
#define TASK_ 80
#define LQ_   1024
#define D_    768
#define HH_   12
#define HD_   64
#define LIN_  4096
#define MQ_   (B_*LQ_)     // 16384 query rows
#define MF_   (B_*LIN_)    // 65536 feat rows
#define QR_   (TASK_+LQ_)  // 1104

// ---- workspace layout (bytes) ----
static constexpr size_t OFF_VAL = 0;                               // bf16 value (B,HH,LIN,HD)
static constexpr size_t OFF_FN  = OFF_VAL + (size_t)MF_*D_*2;      // bf16 fn (MF,768); reused as sampout
static constexpr size_t OFF_QN  = OFF_FN  + (size_t)MF_*D_*2;      // bf16 qn (MQ,768); reused as prep
static constexpr size_t OFF_OA  = OFF_QN  + (size_t)MQ_*D_*2;      // f32 off+attw (MQ,144)
static constexpr size_t OFF_WVT = OFF_OA  + (size_t)MQ_*144*4;     // bf16 W_val^T (768,768)
static constexpr size_t OFF_WOT = OFF_WVT + (size_t)D_*D_*2;       // bf16 W_out^T (768,768)
static constexpr size_t OFF_WCT = OFF_WOT + (size_t)D_*D_*2;       // bf16 Wcat^T (256,768)

__device__ __forceinline__ void async16(const void* g, void* l) {
  __builtin_amdgcn_global_load_lds((const __attribute__((address_space(1))) void*)g,
                                   (__attribute__((address_space(3))) void*)l, 16, 0, 0);
}

// LDS-tiled transpose: W (768x768) f32 row-major -> WT = W^T bf16 row-major
__global__ __launch_bounds__(256) void k_transpose(const float* __restrict__ W, bf16* __restrict__ WT) {
  __shared__ float t[64][65];
  int bx = blockIdx.x % 12, by = blockIdx.x / 12;
  int n0 = bx*64, k0 = by*64;
  int col = threadIdx.x & 63, rg = threadIdx.x >> 6;
  #pragma unroll
  for (int i=0;i<16;++i) { int row = i*4+rg; t[row][col] = W[(size_t)(k0+row)*D_ + n0+col]; }
  __syncthreads();
  #pragma unroll
  for (int i=0;i<16;++i) { int row = i*4+rg; WT[(size_t)(n0+row)*D_ + k0+col] = __float2bfloat16(t[col][row]); }
}

// build Wcat^T (256 x 768): rows 0..95 = W_off cols, 96..143 = W_attw cols, rest 0
__global__ __launch_bounds__(256) void k_wcat(const float* __restrict__ Woff, const float* __restrict__ Wat,
                                              bf16* __restrict__ WT) {
  int idx = blockIdx.x*256 + threadIdx.x;      // over 256*768, exact
  int j = idx / D_, k = idx - j*D_;
  float v = 0.f;
  if (j < 96)       v = Woff[(size_t)k*96 + j];
  else if (j < 144) v = Wat[(size_t)k*48 + (j-96)];
  WT[idx] = __float2bfloat16(v);
}

// LayerNorm one row per block (row length 768), output bf16
__global__ __launch_bounds__(256) void k_ln(const float* __restrict__ x, const float* __restrict__ w,
                                            const float* __restrict__ bia, bf16* __restrict__ out,
                                            int rows_per_batch, int batch_stride, int row_off) {
  int row = blockIdx.x;
  int bat = row / rows_per_batch, r = row - bat*rows_per_batch;
  const float* src = x + (size_t)bat*batch_stride + (size_t)(row_off + r)*D_;
  int t = threadIdx.x;
  float v0 = src[t], v1 = src[t+256], v2 = src[t+512];
  float s = v0+v1+v2, s2 = v0*v0+v1*v1+v2*v2;
  #pragma unroll
  for (int o=32;o>0;o>>=1){ s += __shfl_down(s,o); s2 += __shfl_down(s2,o); }
  __shared__ float rs[4], rq[4];
  int wid = t>>6, ln = t&63;
  if (ln==0){ rs[wid]=s; rq[wid]=s2; }
  __syncthreads();
  s  = rs[0]+rs[1]+rs[2]+rs[3];
  s2 = rq[0]+rq[1]+rq[2]+rq[3];
  float mu  = s*(1.f/D_);
  float var = s2*(1.f/D_) - mu*mu;
  float rstd = rsqrtf(var + 1e-6f);
  bf16* dst = out + (size_t)row*D_;
  dst[t]     = __float2bfloat16((v0-mu)*rstd*w[t]     + bia[t]);
  dst[t+256] = __float2bfloat16((v1-mu)*rstd*w[t+256] + bia[t+256]);
  dst[t+512] = __float2bfloat16((v2-mu)*rstd*w[t+512] + bia[t+512]);
}

// 128x128 tile bf16 MFMA GEMM, A (M,K) row-major, BT (N,K) row-major, K%32==0.
// 3-buffer LDS, depth-2 prefetch, counted vmcnt + raw barrier (no vmcnt(0)
// drain in main loop), XOR bank swizzle, XCD-chunked block swizzle.
template<int MODE>
__global__ __launch_bounds__(256) void k_gemm(const bf16* __restrict__ A, const bf16* __restrict__ BT,
                                              int K,
                                              const float* __restrict__ bias0, const float* __restrict__ bias1,
                                              void* __restrict__ outp,
                                              const float* __restrict__ query, const float* __restrict__ gamma) {
  __shared__ char lds[49152];    // 3 buffers x (A 8KB + B 8KB)
  const int tid = threadIdx.x, wid = tid>>6, lane = tid&63;
  // XCD-chunked swizzle: contiguous logical range per XCD (nwg % 8 == 0),
  // then N-tile fastest within the logical id -> A-panel L2 reuse on one XCD.
  const int nwg = gridDim.x*gridDim.y, ny = gridDim.y;
  const int d = blockIdx.y*gridDim.x + blockIdx.x;
  const int logical = (d & 7)*(nwg>>3) + (d>>3);
  const int bm = (logical/ny)*128, bn = (logical%ny)*128;
  const int wr = wid>>1, wc = wid&1;
  const int c0 = wid*2, c1 = c0+1;
  const int sr0 = c0*16 + (lane>>2), sr1 = sr0+16;
  // source-side XOR swizzle: LDS slot (lane&3) receives global slot (lane&3)^((row>>1)&3)
  const int skb = (((lane&3) ^ ((lane>>3)&3)))*8;
  const bf16* ga0 = A  + (size_t)(bm+sr0)*K + skb;
  const bf16* ga1 = A  + (size_t)(bm+sr1)*K + skb;
  const bf16* gb0 = BT + (size_t)(bn+sr0)*K + skb;
  const bf16* gb1 = BT + (size_t)(bn+sr1)*K + skb;
  // read-side: same XOR on the 16B slot index
  const int rb = (lane&15)*64 + ((((lane>>4) ^ ((lane>>1)&3)))<<4);
  floatx4 acc[4][4] = {};
  auto stage = [&](int k0, char* buf) {
    char* dA = buf; char* dB = buf + 8192;
    async16(ga0+k0, dA + c0*1024); async16(ga1+k0, dA + c1*1024);
    async16(gb0+k0, dB + c0*1024); async16(gb1+k0, dB + c1*1024);
  };
  stage(0,  lds);            // tile 0 -> buf 0
  stage(32, lds + 16384);    // tile 1 -> buf 1
  const int NT = K >> 5;     // 24
  int cur = 0, nxt = 2;
  for (int k = 0; k < NT; ++k) {
    // retire tile k's 4 staging loads (per wave); keep tile k+1's in flight
    if (k < NT-1) asm volatile("s_waitcnt vmcnt(4)" ::: "memory");
    else          asm volatile("s_waitcnt vmcnt(0)" ::: "memory");
    __builtin_amdgcn_s_barrier();          // all waves: buf[cur] fully staged
    __builtin_amdgcn_sched_barrier(0);
    if (k + 2 < NT) {                      // stage tile k+2 (buf safe: its last
      stage((k+2)*32, lds + nxt*16384);    // readers finished before the barrier)
    }
    const char* ldsA = lds + cur*16384; const char* ldsB = ldsA + 8192;
    short8 af[4], bfr[4];
    #pragma unroll
    for (int i=0;i<4;++i) {
      af[i]  = *(const short8*)(ldsA + (wr*64 + i*16)*64 + rb);
      bfr[i] = *(const short8*)(ldsB + (wc*64 + i*16)*64 + rb);
    }
    #pragma unroll
    for (int mi=0;mi<4;++mi)
      #pragma unroll
      for (int ni=0;ni<4;++ni)
        acc[mi][ni] = __builtin_amdgcn_mfma_f32_16x16x32_bf16(af[mi], bfr[ni], acc[mi][ni], 0, 0, 0);
    cur = (cur==2) ? 0 : cur+1;
    nxt = (nxt==2) ? 0 : nxt+1;
  }
  const int rowb = (lane>>4)*4, col = lane&15;
  #pragma unroll
  for (int mi=0;mi<4;++mi) {
    #pragma unroll
    for (int ni=0;ni<4;++ni) {
      const int gn = bn + wc*64 + ni*16 + col;
      #pragma unroll
      for (int r=0;r<4;++r) {
        const int gm = bm + wr*64 + mi*16 + rowb + r;
        float v = acc[mi][ni][r];
        if constexpr (MODE==0) {
          v += bias0[gn];
          int b = gm >> 12, pix = gm & 4095;
          int h = gn >> 6,  hd  = gn & 63;
          ((bf16*)outp)[(((size_t)(b*HH_+h)*LIN_ + pix)<<6) + hd] = __float2bfloat16(v);
        } else if constexpr (MODE==1) {
          if (gn < 144) {
            v += (gn < 96) ? bias0[gn] : bias1[gn-96];
            ((float*)outp)[(size_t)gm*144 + gn] = v;
          }
        } else {
          v += bias0[gn];
          int b = gm >> 10, lq = gm & 1023;
          size_t idx = ((size_t)b*QR_ + TASK_ + lq)*D_ + gn;
          ((float*)outp)[idx] = query[idx] + gamma[gn]*v;
        }
      }
    }
  }
}

// precompute per (m,h,p): 4 corners x {combined weight, clamped pixel index}
__global__ __launch_bounds__(256) void k_prep(const float* __restrict__ oa_all,
                                              const float* __restrict__ refp,
                                              float2* __restrict__ prep) {
  int idx = blockIdx.x*256 + threadIdx.x;     // MQ_*HH_*4 = 786432, exact
  int p = idx & 3, mh = idx >> 2;
  int h = mh % HH_, m = mh / HH_;
  const float* oa = oa_all + (size_t)m*144;
  float l0 = oa[96+h*4+0], l1 = oa[96+h*4+1], l2 = oa[96+h*4+2], l3 = oa[96+h*4+3];
  float mx = fmaxf(fmaxf(l0,l1), fmaxf(l2,l3));
  float e0 = expf(l0-mx), e1 = expf(l1-mx), e2 = expf(l2-mx), e3 = expf(l3-mx);
  float inv = 1.f/(e0+e1+e2+e3);
  float ep = (p==0)?e0:(p==1)?e1:(p==2)?e2:e3;
  float awp = ep*inv;
  float x = refp[(size_t)m*2+0]*64.f - 0.5f + oa[h*8+p*2+0];
  float y = refp[(size_t)m*2+1]*64.f - 0.5f + oa[h*8+p*2+1];
  float x0f = floorf(x), y0f = floorf(y);
  int ix = (int)x0f, iy = (int)y0f;
  float fx = x-x0f, fy = y-y0f;
  float wx[2] = {1.f-fx, fx}, wy[2] = {1.f-fy, fy};
  float2 e[4];
  #pragma unroll
  for (int c=0;c<4;++c) {
    int dx = c&1, dy = c>>1;
    int xc = ix+dx, yc = iy+dy;
    bool valid = ((unsigned)xc < 64u) && ((unsigned)yc < 64u);
    float w = valid ? awp*wx[dx]*wy[dy] : 0.f;
    int xi = min(max(xc,0),63), yi = min(max(yc,0),63);
    e[c].x = w;
    e[c].y = __int_as_float(yi*64+xi);
  }
  float2* dst = prep + (size_t)mh*16 + p*4;
  *(float4*)(dst)   = make_float4(e[0].x, e[0].y, e[1].x, e[1].y);
  *(float4*)(dst+2) = make_float4(e[2].x, e[2].y, e[3].x, e[3].y);
}

// gather+combine: wave = one (m,h) group; lane = (channel_quad<<2) | point
__global__ __launch_bounds__(256) void k_sample(const float2* __restrict__ prep,
                                                const bf16* __restrict__ value,
                                                bf16* __restrict__ sampout) {
  int g  = blockIdx.x*4 + (threadIdx.x>>6);   // (b*1024+q)*12 + h
  int lane = threadIdx.x & 63;
  int cq = lane >> 2, p = lane & 3;
  int h = g % HH_, m = g / HH_;
  int b = m >> 10;
  const float2* pb = prep + (size_t)g*16 + p*4;
  float4 e01 = *(const float4*)(pb);
  float4 e23 = *(const float4*)(pb+2);
  const bf16* vb = value + (((size_t)(b*HH_+h))<<18) + (cq<<2);   // LIN_*HD_ = 262144
  float a0=0.f, a1=0.f, a2=0.f, a3=0.f;
  float wv[4]  = {e01.x, e01.z, e23.x, e23.z};
  int   pix[4] = {__float_as_int(e01.y), __float_as_int(e01.w),
                  __float_as_int(e23.y), __float_as_int(e23.w)};
  #pragma unroll
  for (int c=0;c<4;++c) {
    short4v v = *(const short4v*)(vb + ((size_t)pix[c]<<6));
    float w = wv[c];
    a0 += w*__uint_as_float(((unsigned)(unsigned short)v[0])<<16);
    a1 += w*__uint_as_float(((unsigned)(unsigned short)v[1])<<16);
    a2 += w*__uint_as_float(((unsigned)(unsigned short)v[2])<<16);
    a3 += w*__uint_as_float(((unsigned)(unsigned short)v[3])<<16);
  }
  a0 += __shfl_xor(a0,1); a0 += __shfl_xor(a0,2);
  a1 += __shfl_xor(a1,1); a1 += __shfl_xor(a1,2);
  a2 += __shfl_xor(a2,1); a2 += __shfl_xor(a2,2);
  a3 += __shfl_xor(a3,1); a3 += __shfl_xor(a3,2);
  if (p == 0) {
    short4v o;
    o[0] = (short)__bfloat16_as_ushort(__float2bfloat16(a0));
    o[1] = (short)__bfloat16_as_ushort(__float2bfloat16(a1));
    o[2] = (short)__bfloat16_as_ushort(__float2bfloat16(a2));
    o[3] = (short)__bfloat16_as_ushort(__float2bfloat16(a3));
    *(short4v*)(sampout + (size_t)m*D_ + h*64 + cq*4) = o;
  }
}

// copy the task tokens (first 80 rows per batch) straight through
__global__ __launch_bounds__(256) void k_copytt(const float* __restrict__ query, float* __restrict__ out) {
  int idx = blockIdx.x*256 + threadIdx.x;      // 245760/4 float4, exact
  const int perb = TASK_*D_/4;                 // 15360
  int b = idx / perb, r = idx - b*perb;
  const float4* s = (const float4*)(query + (size_t)b*QR_*D_) + r;
  float4* d = (float4*)(out + (size_t)b*QR_*D_) + r;
  *d = *s;
}

extern "C" void kernel_launch(void* const* d_in, const int* in_sizes, int n_in,
                              void* d_out, int out_size, void* d_ws, size_t ws_size,
                              hipStream_t stream) {
  (void)in_sizes; (void)n_in; (void)out_size; (void)ws_size;
  const float* query = (const float*)d_in[0];
  const float* refp  = (const float*)d_in[1];
  const float* feat  = (const float*)d_in[2];
  const float* qn_w  = (const float*)d_in[5];
  const float* qn_b  = (const float*)d_in[6];
  const float* fn_w  = (const float*)d_in[7];
  const float* fn_b  = (const float*)d_in[8];
  const float* gamma = (const float*)d_in[9];
  const float* W_off = (const float*)d_in[10];
  const float* b_off = (const float*)d_in[11];
  const float* W_attw= (const float*)d_in[12];
  const float* b_attw= (const float*)d_in[13];
  const float* W_val = (const float*)d_in[14];
  const float* b_val = (const float*)d_in[15];
  const float* W_out = (const float*)d_in[16];
  const float* b_out = (const float*)d_in[17];
  char*  ws  = (char*)d_ws;
  float* out = (float*)d_out;

  bf16*   wsVal  = (bf16*)(ws + OFF_VAL);
  bf16*   wsFn   = (bf16*)(ws + OFF_FN);
  bf16*   wsQn   = (bf16*)(ws + OFF_QN);
  float*  wsOA   = (float*)(ws + OFF_OA);
  bf16*   wsWvT  = (bf16*)(ws + OFF_WVT);
  bf16*   wsWoT  = (bf16*)(ws + OFF_WOT);
  bf16*   wsWcT  = (bf16*)(ws + OFF_WCT);
  float2* wsPrep = (float2*)(ws + OFF_QN);   // qn dead after MODE-1 GEMM
  bf16*   wsSamp = wsFn;                     // fn dead after value GEMM

  k_transpose<<<144, 256, 0, stream>>>(W_val, wsWvT);
  k_transpose<<<144, 256, 0, stream>>>(W_out, wsWoT);
  k_wcat<<<768, 256, 0, stream>>>(W_off, W_attw, wsWcT);
  k_ln<<<MQ_, 256, 0, stream>>>(query, qn_w, qn_b, wsQn, LQ_, QR_*D_, TASK_);
  k_ln<<<MF_, 256, 0, stream>>>(feat, fn_w, fn_b, wsFn, LIN_, LIN_*D_, 0);
  k_gemm<1><<<dim3(MQ_/128, 2), 256, 0, stream>>>(wsQn, wsWcT, D_, b_off, b_attw, wsOA, nullptr, nullptr);
  k_prep<<<(MQ_*HH_*4)/256, 256, 0, stream>>>(wsOA, refp, wsPrep);
  k_gemm<0><<<dim3(MF_/128, 6), 256, 0, stream>>>(wsFn, wsWvT, D_, b_val, nullptr, wsVal, nullptr, nullptr);
  k_sample<<<(MQ_*HH_)/4, 256, 0, stream>>>(wsPrep, wsVal, wsSamp);
  k_gemm<2><<<dim3(MQ_/128, 6), 256, 0, stream>>>(wsSamp, wsWoT, D_, b_out, nullptr, out, query, gamma);
  k_copytt<<<(B_*TASK_*D_/4)/256, 256, 0, stream>>>(query, out);
}

// Round 6
// 333.266 us; speedup vs baseline: 1.4455x; 1.0976x over previous
//
#include <hip/hip_runtime.h>
#include <hip/hip_bf16.h>

using bf16 = __hip_bfloat16;
typedef __attribute__((ext_vector_type(8))) short short8;
typedef __attribute__((ext_vector_type(4))) short short4v;
typedef __attribute__((ext_vector_type(4))) float floatx4;

#define B_    16
#define TASK_ 80
#define LQ_   1024
#define D_    768
#define HH_   12
#define HD_   64
#define LIN_  4096
#define MQ_   (B_*LQ_)     // 16384 query rows
#define MF_   (B_*LIN_)    // 65536 feat rows
#define QR_   (TASK_+LQ_)  // 1104

// ---- workspace layout (bytes) ----
static constexpr size_t OFF_VAL = 0;                               // bf16 value (B,HH,LIN,HD)
static constexpr size_t OFF_FN  = OFF_VAL + (size_t)MF_*D_*2;      // bf16 fn (MF,768); reused as sampout
static constexpr size_t OFF_QN  = OFF_FN  + (size_t)MF_*D_*2;      // bf16 qn (MQ,768); reused as prep
static constexpr size_t OFF_OA  = OFF_QN  + (size_t)MQ_*D_*2;      // f32 off+attw (MQ,144)
static constexpr size_t OFF_WVT = OFF_OA  + (size_t)MQ_*144*4;     // bf16 W_val^T (768,768)
static constexpr size_t OFF_WOT = OFF_WVT + (size_t)D_*D_*2;       // bf16 W_out^T (768,768)
static constexpr size_t OFF_WCT = OFF_WOT + (size_t)D_*D_*2;       // bf16 Wcat^T (256,768)

__device__ __forceinline__ void async16(const void* g, void* l) {
  __builtin_amdgcn_global_load_lds((const __attribute__((address_space(1))) void*)g,
                                   (__attribute__((address_space(3))) void*)l, 16, 0, 0);
}

// fused weight prep: blocks 0..143 transpose W_val, 144..287 transpose W_out,
// 288..1055 build Wcat^T
__global__ __launch_bounds__(256) void k_weights(const float* __restrict__ Wv, const float* __restrict__ Wo,
                                                 const float* __restrict__ Woff, const float* __restrict__ Wat,
                                                 bf16* __restrict__ WvT, bf16* __restrict__ WoT,
                                                 bf16* __restrict__ WcT) {
  int bid = blockIdx.x;
  if (bid < 288) {
    const float* W = (bid < 144) ? Wv : Wo;
    bf16* WT = (bid < 144) ? WvT : WoT;
    int lb = (bid < 144) ? bid : bid - 144;
    __shared__ float t[64][65];
    int bx = lb % 12, by = lb / 12;
    int n0 = bx*64, k0 = by*64;
    int col = threadIdx.x & 63, rg = threadIdx.x >> 6;
    #pragma unroll
    for (int i=0;i<16;++i) { int row = i*4+rg; t[row][col] = W[(size_t)(k0+row)*D_ + n0+col]; }
    __syncthreads();
    #pragma unroll
    for (int i=0;i<16;++i) { int row = i*4+rg; WT[(size_t)(n0+row)*D_ + k0+col] = __float2bfloat16(t[col][row]); }
  } else {
    int idx = (bid-288)*256 + threadIdx.x;     // over 256*768, exact
    int j = idx / D_, k = idx - j*D_;
    float v = 0.f;
    if (j < 96)       v = Woff[(size_t)k*96 + j];
    else if (j < 144) v = Wat[(size_t)k*48 + (j-96)];
    WcT[idx] = __float2bfloat16(v);
  }
}

// fused LayerNorm: blocks 0..16383 -> query rows, 16384..81919 -> feat rows
__global__ __launch_bounds__(256) void k_ln(const float* __restrict__ query, const float* __restrict__ feat,
                                            const float* __restrict__ qw, const float* __restrict__ qb,
                                            const float* __restrict__ fw, const float* __restrict__ fb,
                                            bf16* __restrict__ qn, bf16* __restrict__ fn) {
  int row = blockIdx.x;
  const float* src; const float* w; const float* bia; bf16* dst;
  if (row < MQ_) {
    int bat = row >> 10, r = row & 1023;
    src = query + ((size_t)bat*QR_ + TASK_ + r)*D_;
    w = qw; bia = qb; dst = qn + (size_t)row*D_;
  } else {
    int fr = row - MQ_;
    src = feat + (size_t)fr*D_;
    w = fw; bia = fb; dst = fn + (size_t)fr*D_;
  }
  int t = threadIdx.x;
  float v0 = src[t], v1 = src[t+256], v2 = src[t+512];
  float s = v0+v1+v2, s2 = v0*v0+v1*v1+v2*v2;
  #pragma unroll
  for (int o=32;o>0;o>>=1){ s += __shfl_down(s,o); s2 += __shfl_down(s2,o); }
  __shared__ float rs[4], rq[4];
  int wid = t>>6, ln = t&63;
  if (ln==0){ rs[wid]=s; rq[wid]=s2; }
  __syncthreads();
  s  = rs[0]+rs[1]+rs[2]+rs[3];
  s2 = rq[0]+rq[1]+rq[2]+rq[3];
  float mu  = s*(1.f/D_);
  float var = s2*(1.f/D_) - mu*mu;
  float rstd = rsqrtf(var + 1e-6f);
  dst[t]     = __float2bfloat16((v0-mu)*rstd*w[t]     + bia[t]);
  dst[t+256] = __float2bfloat16((v1-mu)*rstd*w[t+256] + bia[t+256]);
  dst[t+512] = __float2bfloat16((v2-mu)*rstd*w[t+512] + bia[t+512]);
}

// 256x256 tile, 8 waves (wave tile 128x64), BK=32, ring-3 LDS, 4-phase
// interleave per K-tile: {1 staging issue | ds_read subtile | 8 MFMA}.
// One counted vmcnt + one barrier per K-tile. MODE 0 (value proj) output.
__global__ __launch_bounds__(512, 2) void k_gemm_val(const bf16* __restrict__ A, const bf16* __restrict__ BT,
                                                     const float* __restrict__ bias0, bf16* __restrict__ outp) {
  __shared__ char lds[98304];    // 3 buffers x (A 16KB + B 16KB)
  const int K = D_;
  const int tid = threadIdx.x, wid = tid>>6, lane = tid&63;
  const int nwg = gridDim.x*gridDim.y;            // 768
  const int d = blockIdx.y*gridDim.x + blockIdx.x;
  const int logical = (d & 7)*(nwg>>3) + (d>>3);  // XCD-chunked
  const int bm = (logical/3)*256, bn = (logical%3)*256;
  const int wm = wid>>2, wn = wid&3;              // wave tile rows [wm*128,+128), cols [wn*64,+64)
  // staging: thread tid covers row tid>>2, 16B slot (tid&3), XOR-swizzled source
  const int srow = tid>>2;
  const int sslot = ((tid&3) ^ ((tid>>3)&3))*8;
  const bf16* gA0 = A  + (size_t)(bm + srow)*K + sslot;
  const bf16* gA1 = A  + (size_t)(bm + 128 + srow)*K + sslot;
  const bf16* gB0 = BT + (size_t)(bn + srow)*K + sslot;
  const bf16* gB1 = BT + (size_t)(bn + 128 + srow)*K + sslot;
  // wave-uniform LDS dest base; HW writes base + lane*16 -> byte tid*16 overall
  const int dstbase = (tid>>6)<<10;
  // read-side fragment offset (row lane&15, XOR'd 16B slot)
  const int rb = (lane&15)*64 + ((((lane>>4) ^ ((lane>>1)&3)))<<4);
  floatx4 acc[8][4] = {};
  auto stageAll = [&](int k0, char* buf) {
    async16(gA0+k0, buf + dstbase);
    async16(gA1+k0, buf + 8192 + dstbase);
    async16(gB0+k0, buf + 16384 + dstbase);
    async16(gB1+k0, buf + 24576 + dstbase);
  };
  stageAll(0,  lds);
  stageAll(32, lds + 32768);
  const int NT = K >> 5;     // 24
  int cur = 0, nxt = 2;
  for (int k = 0; k < NT; ++k) {
    if (k < NT-1) asm volatile("s_waitcnt vmcnt(4)" ::: "memory");
    else          asm volatile("s_waitcnt vmcnt(0)" ::: "memory");
    __builtin_amdgcn_s_barrier();          // buf[cur] fully staged; buf[nxt] free
    __builtin_amdgcn_sched_barrier(0);
    const int kk = (k+2)*32;
    const bool pf = (k+2 < NT);            // wave-uniform
    const char* lA = lds + cur*32768;
    const char* lB = lA + 16384;
    char* bufn = lds + nxt*32768;
    short8 af[8], bfr[4];
    // ---- phase 0: stage A-half0 | read A0-3,B0-1 | quadrant (mh0,nh0)
    if (pf) async16(gA0+kk, bufn + dstbase);
    #pragma unroll
    for (int i=0;i<4;++i) af[i] = *(const short8*)(lA + (wm*128 + i*16)*64 + rb);
    #pragma unroll
    for (int i=0;i<2;++i) bfr[i] = *(const short8*)(lB + (wn*64 + i*16)*64 + rb);
    __builtin_amdgcn_s_setprio(1);
    #pragma unroll
    for (int mi=0;mi<4;++mi)
      #pragma unroll
      for (int ni=0;ni<2;++ni)
        acc[mi][ni] = __builtin_amdgcn_mfma_f32_16x16x32_bf16(af[mi], bfr[ni], acc[mi][ni], 0, 0, 0);
    __builtin_amdgcn_s_setprio(0);
    __builtin_amdgcn_sched_barrier(0);
    // ---- phase 1: stage A-half1 | read B2-3 | quadrant (mh0,nh1)
    if (pf) async16(gA1+kk, bufn + 8192 + dstbase);
    #pragma unroll
    for (int i=2;i<4;++i) bfr[i] = *(const short8*)(lB + (wn*64 + i*16)*64 + rb);
    __builtin_amdgcn_s_setprio(1);
    #pragma unroll
    for (int mi=0;mi<4;++mi)
      #pragma unroll
      for (int ni=2;ni<4;++ni)
        acc[mi][ni] = __builtin_amdgcn_mfma_f32_16x16x32_bf16(af[mi], bfr[ni], acc[mi][ni], 0, 0, 0);
    __builtin_amdgcn_s_setprio(0);
    __builtin_amdgcn_sched_barrier(0);
    // ---- phase 2: stage B-half0 | read A4-7 | quadrant (mh1,nh0)
    if (pf) async16(gB0+kk, bufn + 16384 + dstbase);
    #pragma unroll
    for (int i=4;i<8;++i) af[i] = *(const short8*)(lA + (wm*128 + i*16)*64 + rb);
    __builtin_amdgcn_s_setprio(1);
    #pragma unroll
    for (int mi=4;mi<8;++mi)
      #pragma unroll
      for (int ni=0;ni<2;++ni)
        acc[mi][ni] = __builtin_amdgcn_mfma_f32_16x16x32_bf16(af[mi], bfr[ni], acc[mi][ni], 0, 0, 0);
    __builtin_amdgcn_s_setprio(0);
    __builtin_amdgcn_sched_barrier(0);
    // ---- phase 3: stage B-half1 | quadrant (mh1,nh1)
    if (pf) async16(gB1+kk, bufn + 24576 + dstbase);
    __builtin_amdgcn_s_setprio(1);
    #pragma unroll
    for (int mi=4;mi<8;++mi)
      #pragma unroll
      for (int ni=2;ni<4;++ni)
        acc[mi][ni] = __builtin_amdgcn_mfma_f32_16x16x32_bf16(af[mi], bfr[ni], acc[mi][ni], 0, 0, 0);
    __builtin_amdgcn_s_setprio(0);
    __builtin_amdgcn_sched_barrier(0);
    cur = (cur==2) ? 0 : cur+1;
    nxt = (nxt==2) ? 0 : nxt+1;
  }
  // epilogue: scatter to (b, h, pix, hd) bf16
  const int rowb = (lane>>4)*4, col = lane&15;
  #pragma unroll
  for (int mi=0;mi<8;++mi) {
    #pragma unroll
    for (int ni=0;ni<4;++ni) {
      const int gn = bn + wn*64 + ni*16 + col;
      const float bv = bias0[gn];
      const int h = gn >> 6, hd = gn & 63;
      #pragma unroll
      for (int r=0;r<4;++r) {
        const int gm = bm + wm*128 + mi*16 + rowb + r;
        const int b = gm >> 12, pix = gm & 4095;
        outp[(((size_t)(b*HH_+h)*LIN_ + pix)<<6) + hd] = __float2bfloat16(acc[mi][ni][r] + bv);
      }
    }
  }
}

// 128x128 tile bf16 MFMA GEMM (proven round-4 structure) for MODE 1 / MODE 2.
template<int MODE>
__global__ __launch_bounds__(256) void k_gemm(const bf16* __restrict__ A, const bf16* __restrict__ BT,
                                              int K,
                                              const float* __restrict__ bias0, const float* __restrict__ bias1,
                                              void* __restrict__ outp,
                                              const float* __restrict__ query, const float* __restrict__ gamma) {
  __shared__ char lds[49152];    // 3 buffers x (A 8KB + B 8KB)
  const int tid = threadIdx.x, wid = tid>>6, lane = tid&63;
  const int nwg = gridDim.x*gridDim.y, ny = gridDim.y;
  const int d = blockIdx.y*gridDim.x + blockIdx.x;
  const int logical = (d & 7)*(nwg>>3) + (d>>3);
  const int bm = (logical/ny)*128, bn = (logical%ny)*128;
  const int wr = wid>>1, wc = wid&1;
  const int c0 = wid*2, c1 = c0+1;
  const int sr0 = c0*16 + (lane>>2), sr1 = sr0+16;
  const int skb = (((lane&3) ^ ((lane>>3)&3)))*8;
  const bf16* ga0 = A  + (size_t)(bm+sr0)*K + skb;
  const bf16* ga1 = A  + (size_t)(bm+sr1)*K + skb;
  const bf16* gb0 = BT + (size_t)(bn+sr0)*K + skb;
  const bf16* gb1 = BT + (size_t)(bn+sr1)*K + skb;
  const int rb = (lane&15)*64 + ((((lane>>4) ^ ((lane>>1)&3)))<<4);
  floatx4 acc[4][4] = {};
  auto stage = [&](int k0, char* buf) {
    char* dA = buf; char* dB = buf + 8192;
    async16(ga0+k0, dA + c0*1024); async16(ga1+k0, dA + c1*1024);
    async16(gb0+k0, dB + c0*1024); async16(gb1+k0, dB + c1*1024);
  };
  stage(0,  lds);
  stage(32, lds + 16384);
  const int NT = K >> 5;
  int cur = 0, nxt = 2;
  for (int k = 0; k < NT; ++k) {
    if (k < NT-1) asm volatile("s_waitcnt vmcnt(4)" ::: "memory");
    else          asm volatile("s_waitcnt vmcnt(0)" ::: "memory");
    __builtin_amdgcn_s_barrier();
    __builtin_amdgcn_sched_barrier(0);
    if (k + 2 < NT) stage((k+2)*32, lds + nxt*16384);
    const char* ldsA = lds + cur*16384; const char* ldsB = ldsA + 8192;
    short8 af[4], bfr[4];
    #pragma unroll
    for (int i=0;i<4;++i) {
      af[i]  = *(const short8*)(ldsA + (wr*64 + i*16)*64 + rb);
      bfr[i] = *(const short8*)(ldsB + (wc*64 + i*16)*64 + rb);
    }
    #pragma unroll
    for (int mi=0;mi<4;++mi)
      #pragma unroll
      for (int ni=0;ni<4;++ni)
        acc[mi][ni] = __builtin_amdgcn_mfma_f32_16x16x32_bf16(af[mi], bfr[ni], acc[mi][ni], 0, 0, 0);
    cur = (cur==2) ? 0 : cur+1;
    nxt = (nxt==2) ? 0 : nxt+1;
  }
  const int rowb = (lane>>4)*4, col = lane&15;
  #pragma unroll
  for (int mi=0;mi<4;++mi) {
    #pragma unroll
    for (int ni=0;ni<4;++ni) {
      const int gn = bn + wc*64 + ni*16 + col;
      #pragma unroll
      for (int r=0;r<4;++r) {
        const int gm = bm + wr*64 + mi*16 + rowb + r;
        float v = acc[mi][ni][r];
        if constexpr (MODE==1) {
          if (gn < 144) {
            v += (gn < 96) ? bias0[gn] : bias1[gn-96];
            ((float*)outp)[(size_t)gm*144 + gn] = v;
          }
        } else {
          v += bias0[gn];
          int b = gm >> 10, lq = gm & 1023;
          size_t idx = ((size_t)b*QR_ + TASK_ + lq)*D_ + gn;
          ((float*)outp)[idx] = query[idx] + gamma[gn]*v;
        }
      }
    }
  }
}

// precompute per (m,h,p): 4 corners x {combined weight, clamped pixel index};
// blocks 0..959 additionally copy the task-token rows to d_out
__global__ __launch_bounds__(256) void k_prep(const float* __restrict__ oa_all,
                                              const float* __restrict__ refp,
                                              float2* __restrict__ prep,
                                              const float* __restrict__ query, float* __restrict__ out) {
  int idx = blockIdx.x*256 + threadIdx.x;     // MQ_*HH_*4 = 786432, exact
  int p = idx & 3, mh = idx >> 2;
  int h = mh % HH_, m = mh / HH_;
  const float* oa = oa_all + (size_t)m*144;
  float l0 = oa[96+h*4+0], l1 = oa[96+h*4+1], l2 = oa[96+h*4+2], l3 = oa[96+h*4+3];
  float mx = fmaxf(fmaxf(l0,l1), fmaxf(l2,l3));
  float e0 = expf(l0-mx), e1 = expf(l1-mx), e2 = expf(l2-mx), e3 = expf(l3-mx);
  float inv = 1.f/(e0+e1+e2+e3);
  float ep = (p==0)?e0:(p==1)?e1:(p==2)?e2:e3;
  float awp = ep*inv;
  float x = refp[(size_t)m*2+0]*64.f - 0.5f + oa[h*8+p*2+0];
  float y = refp[(size_t)m*2+1]*64.f - 0.5f + oa[h*8+p*2+1];
  float x0f = floorf(x), y0f = floorf(y);
  int ix = (int)x0f, iy = (int)y0f;
  float fx = x-x0f, fy = y-y0f;
  float wx[2] = {1.f-fx, fx}, wy[2] = {1.f-fy, fy};
  float2 e[4];
  #pragma unroll
  for (int c=0;c<4;++c) {
    int dx = c&1, dy = c>>1;
    int xc = ix+dx, yc = iy+dy;
    bool valid = ((unsigned)xc < 64u) && ((unsigned)yc < 64u);
    float w = valid ? awp*wx[dx]*wy[dy] : 0.f;
    int xi = min(max(xc,0),63), yi = min(max(yc,0),63);
    e[c].x = w;
    e[c].y = __int_as_float(yi*64+xi);
  }
  float2* dst = prep + (size_t)mh*16 + p*4;
  *(float4*)(dst)   = make_float4(e[0].x, e[0].y, e[1].x, e[1].y);
  *(float4*)(dst+2) = make_float4(e[2].x, e[2].y, e[3].x, e[3].y);
  // task-token passthrough: B_*TASK_*D_/4 = 245760 float4 -> 960 blocks
  if (blockIdx.x < 960) {
    int ci = blockIdx.x*256 + threadIdx.x;
    const int perb = TASK_*D_/4;               // 15360 float4 per batch
    int b = ci / perb, r = ci - b*perb;
    const float4* s = (const float4*)(query + (size_t)b*QR_*D_) + r;
    float4* dd = (float4*)(out + (size_t)b*QR_*D_) + r;
    *dd = *s;
  }
}

// gather+combine: wave = one (m,h) group; lane = (channel_quad<<2) | point
__global__ __launch_bounds__(256) void k_sample(const float2* __restrict__ prep,
                                                const bf16* __restrict__ value,
                                                bf16* __restrict__ sampout) {
  int g  = blockIdx.x*4 + (threadIdx.x>>6);   // (b*1024+q)*12 + h
  int lane = threadIdx.x & 63;
  int cq = lane >> 2, p = lane & 3;
  int h = g % HH_, m = g / HH_;
  int b = m >> 10;
  const float2* pb = prep + (size_t)g*16 + p*4;
  float4 e01 = *(const float4*)(pb);
  float4 e23 = *(const float4*)(pb+2);
  const bf16* vb = value + (((size_t)(b*HH_+h))<<18) + (cq<<2);   // LIN_*HD_ = 262144
  float a0=0.f, a1=0.f, a2=0.f, a3=0.f;
  float wv[4]  = {e01.x, e01.z, e23.x, e23.z};
  int   pix[4] = {__float_as_int(e01.y), __float_as_int(e01.w),
                  __float_as_int(e23.y), __float_as_int(e23.w)};
  #pragma unroll
  for (int c=0;c<4;++c) {
    short4v v = *(const short4v*)(vb + ((size_t)pix[c]<<6));
    float w = wv[c];
    a0 += w*__uint_as_float(((unsigned)(unsigned short)v[0])<<16);
    a1 += w*__uint_as_float(((unsigned)(unsigned short)v[1])<<16);
    a2 += w*__uint_as_float(((unsigned)(unsigned short)v[2])<<16);
    a3 += w*__uint_as_float(((unsigned)(unsigned short)v[3])<<16);
  }
  a0 += __shfl_xor(a0,1); a0 += __shfl_xor(a0,2);
  a1 += __shfl_xor(a1,1); a1 += __shfl_xor(a1,2);
  a2 += __shfl_xor(a2,1); a2 += __shfl_xor(a2,2);
  a3 += __shfl_xor(a3,1); a3 += __shfl_xor(a3,2);
  if (p == 0) {
    short4v o;
    o[0] = (short)__bfloat16_as_ushort(__float2bfloat16(a0));
    o[1] = (short)__bfloat16_as_ushort(__float2bfloat16(a1));
    o[2] = (short)__bfloat16_as_ushort(__float2bfloat16(a2));
    o[3] = (short)__bfloat16_as_ushort(__float2bfloat16(a3));
    *(short4v*)(sampout + (size_t)m*D_ + h*64 + cq*4) = o;
  }
}

extern "C" void kernel_launch(void* const* d_in, const int* in_sizes, int n_in,
                              void* d_out, int out_size, void* d_ws, size_t ws_size,
                              hipStream_t stream) {
  (void)in_sizes; (void)n_in; (void)out_size; (void)ws_size;
  const float* query = (const float*)d_in[0];
  const float* refp  = (const float*)d_in[1];
  const float* feat  = (const float*)d_in[2];
  const float* qn_w  = (const float*)d_in[5];
  const float* qn_b  = (const float*)d_in[6];
  const float* fn_w  = (const float*)d_in[7];
  const float* fn_b  = (const float*)d_in[8];
  const float* gamma = (const float*)d_in[9];
  const float* W_off = (const float*)d_in[10];
  const float* b_off = (const float*)d_in[11];
  const float* W_attw= (const float*)d_in[12];
  const float* b_attw= (const float*)d_in[13];
  const float* W_val = (const float*)d_in[14];
  const float* b_val = (const float*)d_in[15];
  const float* W_out = (const float*)d_in[16];
  const float* b_out = (const float*)d_in[17];
  char*  ws  = (char*)d_ws;
  float* out = (float*)d_out;

  bf16*   wsVal  = (bf16*)(ws + OFF_VAL);
  bf16*   wsFn   = (bf16*)(ws + OFF_FN);
  bf16*   wsQn   = (bf16*)(ws + OFF_QN);
  float*  wsOA   = (float*)(ws + OFF_OA);
  bf16*   wsWvT  = (bf16*)(ws + OFF_WVT);
  bf16*   wsWoT  = (bf16*)(ws + OFF_WOT);
  bf16*   wsWcT  = (bf16*)(ws + OFF_WCT);
  float2* wsPrep = (float2*)(ws + OFF_QN);   // qn dead after MODE-1 GEMM
  bf16*   wsSamp = wsFn;                     // fn dead after value GEMM

  k_weights<<<1056, 256, 0, stream>>>(W_val, W_out, W_off, W_attw, wsWvT, wsWoT, wsWcT);
  k_ln<<<MQ_+MF_, 256, 0, stream>>>(query, feat, qn_w, qn_b, fn_w, fn_b, wsQn, wsFn);
  k_gemm<1><<<dim3(MQ_/128, 2), 256, 0, stream>>>(wsQn, wsWcT, D_, b_off, b_attw, wsOA, nullptr, nullptr);
  k_prep<<<(MQ_*HH_*4)/256, 256, 0, stream>>>(wsOA, refp, wsPrep, query, out);
  k_gemm_val<<<dim3(MF_/256, 3), 512, 0, stream>>>(wsFn, wsWvT, b_val, wsVal);
  k_sample<<<(MQ_*HH_)/4, 256, 0, stream>>>(wsPrep, wsVal, wsSamp);
  k_gemm<2><<<dim3(MQ_/128, 6), 256, 0, stream>>>(wsSamp, wsWoT, D_, b_out, nullptr, out, query, gamma);
}

// Round 7
// 309.625 us; speedup vs baseline: 1.5558x; 1.0764x over previous
//
#include <hip/hip_runtime.h>
#include <hip/hip_bf16.h>

using bf16 = __hip_bfloat16;
typedef __attribute__((ext_vector_type(8))) short short8;
typedef __attribute__((ext_vector_type(4))) short short4v;
typedef __attribute__((ext_vector_type(4))) float floatx4;

#define B_    16
#define TASK_ 80
#define LQ_   1024
#define D_    768
#define HH_   12
#define HD_   64
#define LIN_  4096
#define MQ_   (B_*LQ_)     // 16384 query rows
#define MF_   (B_*LIN_)    // 65536 feat rows
#define QR_   (TASK_+LQ_)  // 1104

// ---- workspace layout (bytes) ----
static constexpr size_t OFF_VAL = 0;                               // bf16 value (B,HH,LIN,HD)
static constexpr size_t OFF_FN  = OFF_VAL + (size_t)MF_*D_*2;      // bf16 fn (MF,768); reused as sampout
static constexpr size_t OFF_QN  = OFF_FN  + (size_t)MF_*D_*2;      // bf16 qn (MQ,768); reused as prep
static constexpr size_t OFF_OA  = OFF_QN  + (size_t)MQ_*D_*2;      // f32 off+attw (MQ,144)
static constexpr size_t OFF_WVT = OFF_OA  + (size_t)MQ_*144*4;     // bf16 W_val^T (768,768)
static constexpr size_t OFF_WOT = OFF_WVT + (size_t)D_*D_*2;       // bf16 W_out^T (768,768)
static constexpr size_t OFF_WCT = OFF_WOT + (size_t)D_*D_*2;       // bf16 Wcat^T (256,768)

__device__ __forceinline__ void async16(const void* g, void* l) {
  __builtin_amdgcn_global_load_lds((const __attribute__((address_space(1))) void*)g,
                                   (__attribute__((address_space(3))) void*)l, 16, 0, 0);
}

// fused weight prep: blocks 0..143 transpose W_val, 144..287 transpose W_out,
// 288..1055 build Wcat^T
__global__ __launch_bounds__(256) void k_weights(const float* __restrict__ Wv, const float* __restrict__ Wo,
                                                 const float* __restrict__ Woff, const float* __restrict__ Wat,
                                                 bf16* __restrict__ WvT, bf16* __restrict__ WoT,
                                                 bf16* __restrict__ WcT) {
  int bid = blockIdx.x;
  if (bid < 288) {
    const float* W = (bid < 144) ? Wv : Wo;
    bf16* WT = (bid < 144) ? WvT : WoT;
    int lb = (bid < 144) ? bid : bid - 144;
    __shared__ float t[64][65];
    int bx = lb % 12, by = lb / 12;
    int n0 = bx*64, k0 = by*64;
    int col = threadIdx.x & 63, rg = threadIdx.x >> 6;
    #pragma unroll
    for (int i=0;i<16;++i) { int row = i*4+rg; t[row][col] = W[(size_t)(k0+row)*D_ + n0+col]; }
    __syncthreads();
    #pragma unroll
    for (int i=0;i<16;++i) { int row = i*4+rg; WT[(size_t)(n0+row)*D_ + k0+col] = __float2bfloat16(t[col][row]); }
  } else {
    int idx = (bid-288)*256 + threadIdx.x;     // over 256*768, exact
    int j = idx / D_, k = idx - j*D_;
    float v = 0.f;
    if (j < 96)       v = Woff[(size_t)k*96 + j];
    else if (j < 144) v = Wat[(size_t)k*48 + (j-96)];
    WcT[idx] = __float2bfloat16(v);
  }
}

// wave-per-row LayerNorm: rows 0..16383 -> query rows, 16384..81919 -> feat.
// One 64-lane wave per 768-float row: 3x float4 loads, shfl_xor butterfly,
// 3x short4v stores. No LDS, no __syncthreads.
__global__ __launch_bounds__(256) void k_ln(const float* __restrict__ query, const float* __restrict__ feat,
                                            const float* __restrict__ qw, const float* __restrict__ qb,
                                            const float* __restrict__ fw, const float* __restrict__ fb,
                                            bf16* __restrict__ qn, bf16* __restrict__ fn) {
  int r = blockIdx.x*4 + (threadIdx.x>>6);
  int lane = threadIdx.x & 63;
  const float* src; const float* w; const float* bia; bf16* dst;
  if (r < MQ_) {
    int bat = r >> 10, rr = r & 1023;
    src = query + ((size_t)bat*QR_ + TASK_ + rr)*D_;
    w = qw; bia = qb; dst = qn + (size_t)r*D_;
  } else {
    int fr = r - MQ_;
    src = feat + (size_t)fr*D_;
    w = fw; bia = fb; dst = fn + (size_t)fr*D_;
  }
  float4 v[3];
  #pragma unroll
  for (int j=0;j<3;++j) v[j] = ((const float4*)src)[lane + 64*j];
  float s = 0.f, s2 = 0.f;
  #pragma unroll
  for (int j=0;j<3;++j) {
    s  += v[j].x + v[j].y + v[j].z + v[j].w;
    s2 += v[j].x*v[j].x + v[j].y*v[j].y + v[j].z*v[j].z + v[j].w*v[j].w;
  }
  #pragma unroll
  for (int o=32;o>0;o>>=1){ s += __shfl_xor(s,o); s2 += __shfl_xor(s2,o); }
  float mu  = s*(1.f/D_);
  float var = s2*(1.f/D_) - mu*mu;
  float rstd = rsqrtf(var + 1e-6f);
  #pragma unroll
  for (int j=0;j<3;++j) {
    float4 ww = ((const float4*)w)[lane + 64*j];
    float4 bb = ((const float4*)bia)[lane + 64*j];
    short4v o4;
    o4[0] = (short)__bfloat16_as_ushort(__float2bfloat16((v[j].x-mu)*rstd*ww.x + bb.x));
    o4[1] = (short)__bfloat16_as_ushort(__float2bfloat16((v[j].y-mu)*rstd*ww.y + bb.y));
    o4[2] = (short)__bfloat16_as_ushort(__float2bfloat16((v[j].z-mu)*rstd*ww.z + bb.z));
    o4[3] = (short)__bfloat16_as_ushort(__float2bfloat16((v[j].w-mu)*rstd*ww.w + bb.w));
    *(short4v*)(dst + 4*(lane + 64*j)) = o4;
  }
}

// 256x256 tile, 8 waves (wave tile 128x64), BK=32, ring-3 LDS, 4-phase
// interleave per K-tile: {1 staging issue | ds_read subtile | 8 MFMA}.
// One counted vmcnt + one barrier per K-tile. MODE 0 (value proj) output.
__global__ __launch_bounds__(512, 2) void k_gemm_val(const bf16* __restrict__ A, const bf16* __restrict__ BT,
                                                     const float* __restrict__ bias0, bf16* __restrict__ outp) {
  __shared__ char lds[98304];    // 3 buffers x (A 16KB + B 16KB)
  const int K = D_;
  const int tid = threadIdx.x, wid = tid>>6, lane = tid&63;
  const int nwg = gridDim.x*gridDim.y;            // 768
  const int d = blockIdx.y*gridDim.x + blockIdx.x;
  const int logical = (d & 7)*(nwg>>3) + (d>>3);  // XCD-chunked
  const int bm = (logical/3)*256, bn = (logical%3)*256;
  const int wm = wid>>2, wn = wid&3;              // wave tile rows [wm*128,+128), cols [wn*64,+64)
  // staging: thread tid covers row tid>>2, 16B slot (tid&3), XOR-swizzled source
  const int srow = tid>>2;
  const int sslot = ((tid&3) ^ ((tid>>3)&3))*8;
  const bf16* gA0 = A  + (size_t)(bm + srow)*K + sslot;
  const bf16* gA1 = A  + (size_t)(bm + 128 + srow)*K + sslot;
  const bf16* gB0 = BT + (size_t)(bn + srow)*K + sslot;
  const bf16* gB1 = BT + (size_t)(bn + 128 + srow)*K + sslot;
  // wave-uniform LDS dest base; HW writes base + lane*16 -> byte tid*16 overall
  const int dstbase = (tid>>6)<<10;
  // read-side fragment offset (row lane&15, XOR'd 16B slot)
  const int rb = (lane&15)*64 + ((((lane>>4) ^ ((lane>>1)&3)))<<4);
  floatx4 acc[8][4] = {};
  auto stageAll = [&](int k0, char* buf) {
    async16(gA0+k0, buf + dstbase);
    async16(gA1+k0, buf + 8192 + dstbase);
    async16(gB0+k0, buf + 16384 + dstbase);
    async16(gB1+k0, buf + 24576 + dstbase);
  };
  stageAll(0,  lds);
  stageAll(32, lds + 32768);
  const int NT = K >> 5;     // 24
  int cur = 0, nxt = 2;
  for (int k = 0; k < NT; ++k) {
    if (k < NT-1) asm volatile("s_waitcnt vmcnt(4)" ::: "memory");
    else          asm volatile("s_waitcnt vmcnt(0)" ::: "memory");
    __builtin_amdgcn_s_barrier();          // buf[cur] fully staged; buf[nxt] free
    __builtin_amdgcn_sched_barrier(0);
    const int kk = (k+2)*32;
    const bool pf = (k+2 < NT);            // wave-uniform
    const char* lA = lds + cur*32768;
    const char* lB = lA + 16384;
    char* bufn = lds + nxt*32768;
    short8 af[8], bfr[4];
    // ---- phase 0: stage A-half0 | read A0-3,B0-1 | quadrant (mh0,nh0)
    if (pf) async16(gA0+kk, bufn + dstbase);
    #pragma unroll
    for (int i=0;i<4;++i) af[i] = *(const short8*)(lA + (wm*128 + i*16)*64 + rb);
    #pragma unroll
    for (int i=0;i<2;++i) bfr[i] = *(const short8*)(lB + (wn*64 + i*16)*64 + rb);
    __builtin_amdgcn_s_setprio(1);
    #pragma unroll
    for (int mi=0;mi<4;++mi)
      #pragma unroll
      for (int ni=0;ni<2;++ni)
        acc[mi][ni] = __builtin_amdgcn_mfma_f32_16x16x32_bf16(af[mi], bfr[ni], acc[mi][ni], 0, 0, 0);
    __builtin_amdgcn_s_setprio(0);
    __builtin_amdgcn_sched_barrier(0);
    // ---- phase 1: stage A-half1 | read B2-3 | quadrant (mh0,nh1)
    if (pf) async16(gA1+kk, bufn + 8192 + dstbase);
    #pragma unroll
    for (int i=2;i<4;++i) bfr[i] = *(const short8*)(lB + (wn*64 + i*16)*64 + rb);
    __builtin_amdgcn_s_setprio(1);
    #pragma unroll
    for (int mi=0;mi<4;++mi)
      #pragma unroll
      for (int ni=2;ni<4;++ni)
        acc[mi][ni] = __builtin_amdgcn_mfma_f32_16x16x32_bf16(af[mi], bfr[ni], acc[mi][ni], 0, 0, 0);
    __builtin_amdgcn_s_setprio(0);
    __builtin_amdgcn_sched_barrier(0);
    // ---- phase 2: stage B-half0 | read A4-7 | quadrant (mh1,nh0)
    if (pf) async16(gB0+kk, bufn + 16384 + dstbase);
    #pragma unroll
    for (int i=4;i<8;++i) af[i] = *(const short8*)(lA + (wm*128 + i*16)*64 + rb);
    __builtin_amdgcn_s_setprio(1);
    #pragma unroll
    for (int mi=4;mi<8;++mi)
      #pragma unroll
      for (int ni=0;ni<2;++ni)
        acc[mi][ni] = __builtin_amdgcn_mfma_f32_16x16x32_bf16(af[mi], bfr[ni], acc[mi][ni], 0, 0, 0);
    __builtin_amdgcn_s_setprio(0);
    __builtin_amdgcn_sched_barrier(0);
    // ---- phase 3: stage B-half1 | quadrant (mh1,nh1)
    if (pf) async16(gB1+kk, bufn + 24576 + dstbase);
    __builtin_amdgcn_s_setprio(1);
    #pragma unroll
    for (int mi=4;mi<8;++mi)
      #pragma unroll
      for (int ni=2;ni<4;++ni)
        acc[mi][ni] = __builtin_amdgcn_mfma_f32_16x16x32_bf16(af[mi], bfr[ni], acc[mi][ni], 0, 0, 0);
    __builtin_amdgcn_s_setprio(0);
    __builtin_amdgcn_sched_barrier(0);
    cur = (cur==2) ? 0 : cur+1;
    nxt = (nxt==2) ? 0 : nxt+1;
  }
  // epilogue: scatter to (b, h, pix, hd) bf16
  const int rowb = (lane>>4)*4, col = lane&15;
  #pragma unroll
  for (int mi=0;mi<8;++mi) {
    #pragma unroll
    for (int ni=0;ni<4;++ni) {
      const int gn = bn + wn*64 + ni*16 + col;
      const float bv = bias0[gn];
      const int h = gn >> 6, hd = gn & 63;
      #pragma unroll
      for (int r=0;r<4;++r) {
        const int gm = bm + wm*128 + mi*16 + rowb + r;
        const int b = gm >> 12, pix = gm & 4095;
        outp[(((size_t)(b*HH_+h)*LIN_ + pix)<<6) + hd] = __float2bfloat16(acc[mi][ni][r] + bv);
      }
    }
  }
}

// 128x128 tile bf16 MFMA GEMM (proven round-4 structure) for MODE 1 / MODE 2.
template<int MODE>
__global__ __launch_bounds__(256) void k_gemm(const bf16* __restrict__ A, const bf16* __restrict__ BT,
                                              int K,
                                              const float* __restrict__ bias0, const float* __restrict__ bias1,
                                              void* __restrict__ outp,
                                              const float* __restrict__ query, const float* __restrict__ gamma) {
  __shared__ char lds[49152];    // 3 buffers x (A 8KB + B 8KB)
  const int tid = threadIdx.x, wid = tid>>6, lane = tid&63;
  const int nwg = gridDim.x*gridDim.y, ny = gridDim.y;
  const int d = blockIdx.y*gridDim.x + blockIdx.x;
  const int logical = (d & 7)*(nwg>>3) + (d>>3);
  const int bm = (logical/ny)*128, bn = (logical%ny)*128;
  const int wr = wid>>1, wc = wid&1;
  const int c0 = wid*2, c1 = c0+1;
  const int sr0 = c0*16 + (lane>>2), sr1 = sr0+16;
  const int skb = (((lane&3) ^ ((lane>>3)&3)))*8;
  const bf16* ga0 = A  + (size_t)(bm+sr0)*K + skb;
  const bf16* ga1 = A  + (size_t)(bm+sr1)*K + skb;
  const bf16* gb0 = BT + (size_t)(bn+sr0)*K + skb;
  const bf16* gb1 = BT + (size_t)(bn+sr1)*K + skb;
  const int rb = (lane&15)*64 + ((((lane>>4) ^ ((lane>>1)&3)))<<4);
  floatx4 acc[4][4] = {};
  auto stage = [&](int k0, char* buf) {
    char* dA = buf; char* dB = buf + 8192;
    async16(ga0+k0, dA + c0*1024); async16(ga1+k0, dA + c1*1024);
    async16(gb0+k0, dB + c0*1024); async16(gb1+k0, dB + c1*1024);
  };
  stage(0,  lds);
  stage(32, lds + 16384);
  const int NT = K >> 5;
  int cur = 0, nxt = 2;
  for (int k = 0; k < NT; ++k) {
    if (k < NT-1) asm volatile("s_waitcnt vmcnt(4)" ::: "memory");
    else          asm volatile("s_waitcnt vmcnt(0)" ::: "memory");
    __builtin_amdgcn_s_barrier();
    __builtin_amdgcn_sched_barrier(0);
    if (k + 2 < NT) stage((k+2)*32, lds + nxt*16384);
    const char* ldsA = lds + cur*16384; const char* ldsB = ldsA + 8192;
    short8 af[4], bfr[4];
    #pragma unroll
    for (int i=0;i<4;++i) {
      af[i]  = *(const short8*)(ldsA + (wr*64 + i*16)*64 + rb);
      bfr[i] = *(const short8*)(ldsB + (wc*64 + i*16)*64 + rb);
    }
    #pragma unroll
    for (int mi=0;mi<4;++mi)
      #pragma unroll
      for (int ni=0;ni<4;++ni)
        acc[mi][ni] = __builtin_amdgcn_mfma_f32_16x16x32_bf16(af[mi], bfr[ni], acc[mi][ni], 0, 0, 0);
    cur = (cur==2) ? 0 : cur+1;
    nxt = (nxt==2) ? 0 : nxt+1;
  }
  const int rowb = (lane>>4)*4, col = lane&15;
  #pragma unroll
  for (int mi=0;mi<4;++mi) {
    #pragma unroll
    for (int ni=0;ni<4;++ni) {
      const int gn = bn + wc*64 + ni*16 + col;
      #pragma unroll
      for (int r=0;r<4;++r) {
        const int gm = bm + wr*64 + mi*16 + rowb + r;
        float v = acc[mi][ni][r];
        if constexpr (MODE==1) {
          if (gn < 144) {
            v += (gn < 96) ? bias0[gn] : bias1[gn-96];
            ((float*)outp)[(size_t)gm*144 + gn] = v;
          }
        } else {
          v += bias0[gn];
          int b = gm >> 10, lq = gm & 1023;
          size_t idx = ((size_t)b*QR_ + TASK_ + lq)*D_ + gn;
          ((float*)outp)[idx] = query[idx] + gamma[gn]*v;
        }
      }
    }
  }
}

// precompute per (m,h,p): 4 corners x {combined weight, clamped pixel index};
// blocks 0..959 additionally copy the task-token rows to d_out
__global__ __launch_bounds__(256) void k_prep(const float* __restrict__ oa_all,
                                              const float* __restrict__ refp,
                                              float2* __restrict__ prep,
                                              const float* __restrict__ query, float* __restrict__ out) {
  int idx = blockIdx.x*256 + threadIdx.x;     // MQ_*HH_*4 = 786432, exact
  int p = idx & 3, mh = idx >> 2;
  int h = mh % HH_, m = mh / HH_;
  const float* oa = oa_all + (size_t)m*144;
  float l0 = oa[96+h*4+0], l1 = oa[96+h*4+1], l2 = oa[96+h*4+2], l3 = oa[96+h*4+3];
  float mx = fmaxf(fmaxf(l0,l1), fmaxf(l2,l3));
  float e0 = expf(l0-mx), e1 = expf(l1-mx), e2 = expf(l2-mx), e3 = expf(l3-mx);
  float inv = 1.f/(e0+e1+e2+e3);
  float ep = (p==0)?e0:(p==1)?e1:(p==2)?e2:e3;
  float awp = ep*inv;
  float x = refp[(size_t)m*2+0]*64.f - 0.5f + oa[h*8+p*2+0];
  float y = refp[(size_t)m*2+1]*64.f - 0.5f + oa[h*8+p*2+1];
  float x0f = floorf(x), y0f = floorf(y);
  int ix = (int)x0f, iy = (int)y0f;
  float fx = x-x0f, fy = y-y0f;
  float wx[2] = {1.f-fx, fx}, wy[2] = {1.f-fy, fy};
  float2 e[4];
  #pragma unroll
  for (int c=0;c<4;++c) {
    int dx = c&1, dy = c>>1;
    int xc = ix+dx, yc = iy+dy;
    bool valid = ((unsigned)xc < 64u) && ((unsigned)yc < 64u);
    float w = valid ? awp*wx[dx]*wy[dy] : 0.f;
    int xi = min(max(xc,0),63), yi = min(max(yc,0),63);
    e[c].x = w;
    e[c].y = __int_as_float(yi*64+xi);
  }
  float2* dst = prep + (size_t)mh*16 + p*4;
  *(float4*)(dst)   = make_float4(e[0].x, e[0].y, e[1].x, e[1].y);
  *(float4*)(dst+2) = make_float4(e[2].x, e[2].y, e[3].x, e[3].y);
  // task-token passthrough: B_*TASK_*D_/4 = 245760 float4 -> 960 blocks
  if (blockIdx.x < 960) {
    int ci = blockIdx.x*256 + threadIdx.x;
    const int perb = TASK_*D_/4;               // 15360 float4 per batch
    int b = ci / perb, r = ci - b*perb;
    const float4* s = (const float4*)(query + (size_t)b*QR_*D_) + r;
    float4* dd = (float4*)(out + (size_t)b*QR_*D_) + r;
    *dd = *s;
  }
}

// gather+combine: wave = one (m,h) group; lane = (channel_quad<<2) | point
__global__ __launch_bounds__(256) void k_sample(const float2* __restrict__ prep,
                                                const bf16* __restrict__ value,
                                                bf16* __restrict__ sampout) {
  int g  = blockIdx.x*4 + (threadIdx.x>>6);   // (b*1024+q)*12 + h
  int lane = threadIdx.x & 63;
  int cq = lane >> 2, p = lane & 3;
  int h = g % HH_, m = g / HH_;
  int b = m >> 10;
  const float2* pb = prep + (size_t)g*16 + p*4;
  float4 e01 = *(const float4*)(pb);
  float4 e23 = *(const float4*)(pb+2);
  const bf16* vb = value + (((size_t)(b*HH_+h))<<18) + (cq<<2);   // LIN_*HD_ = 262144
  float a0=0.f, a1=0.f, a2=0.f, a3=0.f;
  float wv[4]  = {e01.x, e01.z, e23.x, e23.z};
  int   pix[4] = {__float_as_int(e01.y), __float_as_int(e01.w),
                  __float_as_int(e23.y), __float_as_int(e23.w)};
  #pragma unroll
  for (int c=0;c<4;++c) {
    short4v v = *(const short4v*)(vb + ((size_t)pix[c]<<6));
    float w = wv[c];
    a0 += w*__uint_as_float(((unsigned)(unsigned short)v[0])<<16);
    a1 += w*__uint_as_float(((unsigned)(unsigned short)v[1])<<16);
    a2 += w*__uint_as_float(((unsigned)(unsigned short)v[2])<<16);
    a3 += w*__uint_as_float(((unsigned)(unsigned short)v[3])<<16);
  }
  a0 += __shfl_xor(a0,1); a0 += __shfl_xor(a0,2);
  a1 += __shfl_xor(a1,1); a1 += __shfl_xor(a1,2);
  a2 += __shfl_xor(a2,1); a2 += __shfl_xor(a2,2);
  a3 += __shfl_xor(a3,1); a3 += __shfl_xor(a3,2);
  if (p == 0) {
    short4v o;
    o[0] = (short)__bfloat16_as_ushort(__float2bfloat16(a0));
    o[1] = (short)__bfloat16_as_ushort(__float2bfloat16(a1));
    o[2] = (short)__bfloat16_as_ushort(__float2bfloat16(a2));
    o[3] = (short)__bfloat16_as_ushort(__float2bfloat16(a3));
    *(short4v*)(sampout + (size_t)m*D_ + h*64 + cq*4) = o;
  }
}

extern "C" void kernel_launch(void* const* d_in, const int* in_sizes, int n_in,
                              void* d_out, int out_size, void* d_ws, size_t ws_size,
                              hipStream_t stream) {
  (void)in_sizes; (void)n_in; (void)out_size; (void)ws_size;
  const float* query = (const float*)d_in[0];
  const float* refp  = (const float*)d_in[1];
  const float* feat  = (const float*)d_in[2];
  const float* qn_w  = (const float*)d_in[5];
  const float* qn_b  = (const float*)d_in[6];
  const float* fn_w  = (const float*)d_in[7];
  const float* fn_b  = (const float*)d_in[8];
  const float* gamma = (const float*)d_in[9];
  const float* W_off = (const float*)d_in[10];
  const float* b_off = (const float*)d_in[11];
  const float* W_attw= (const float*)d_in[12];
  const float* b_attw= (const float*)d_in[13];
  const float* W_val = (const float*)d_in[14];
  const float* b_val = (const float*)d_in[15];
  const float* W_out = (const float*)d_in[16];
  const float* b_out = (const float*)d_in[17];
  char*  ws  = (char*)d_ws;
  float* out = (float*)d_out;

  bf16*   wsVal  = (bf16*)(ws + OFF_VAL);
  bf16*   wsFn   = (bf16*)(ws + OFF_FN);
  bf16*   wsQn   = (bf16*)(ws + OFF_QN);
  float*  wsOA   = (float*)(ws + OFF_OA);
  bf16*   wsWvT  = (bf16*)(ws + OFF_WVT);
  bf16*   wsWoT  = (bf16*)(ws + OFF_WOT);
  bf16*   wsWcT  = (bf16*)(ws + OFF_WCT);
  float2* wsPrep = (float2*)(ws + OFF_QN);   // qn dead after MODE-1 GEMM
  bf16*   wsSamp = wsFn;                     // fn dead after value GEMM

  k_weights<<<1056, 256, 0, stream>>>(W_val, W_out, W_off, W_attw, wsWvT, wsWoT, wsWcT);
  k_ln<<<(MQ_+MF_)/4, 256, 0, stream>>>(query, feat, qn_w, qn_b, fn_w, fn_b, wsQn, wsFn);
  k_gemm<1><<<dim3(MQ_/128, 2), 256, 0, stream>>>(wsQn, wsWcT, D_, b_off, b_attw, wsOA, nullptr, nullptr);
  k_prep<<<(MQ_*HH_*4)/256, 256, 0, stream>>>(wsOA, refp, wsPrep, query, out);
  k_gemm_val<<<dim3(MF_/256, 3), 512, 0, stream>>>(wsFn, wsWvT, b_val, wsVal);
  k_sample<<<(MQ_*HH_)/4, 256, 0, stream>>>(wsPrep, wsVal, wsSamp);
  k_gemm<2><<<dim3(MQ_/128, 6), 256, 0, stream>>>(wsSamp, wsWoT, D_, b_out, nullptr, out, query, gamma);
}

// Round 8
// 275.877 us; speedup vs baseline: 1.7462x; 1.1223x over previous
//
#include <hip/hip_runtime.h>
#include <hip/hip_bf16.h>

using bf16 = __hip_bfloat16;
typedef __attribute__((ext_vector_type(8))) short short8;
typedef __attribute__((ext_vector_type(4))) short short4v;
typedef __attribute__((ext_vector_type(4))) float floatx4;

#define B_    16
#define TASK_ 80
#define LQ_   1024
#define D_    768
#define HH_   12
#define HD_   64
#define LIN_  4096
#define MQ_   (B_*LQ_)     // 16384 query rows
#define MF_   (B_*LIN_)    // 65536 feat rows
#define QR_   (TASK_+LQ_)  // 1104

// ---- workspace layout (bytes) ----
static constexpr size_t OFF_VAL = 0;                               // bf16 value (B,HH,LIN,HD)
static constexpr size_t OFF_FN  = OFF_VAL + (size_t)MF_*D_*2;      // bf16 fn (MF,768); reused as sampout
static constexpr size_t OFF_QN  = OFF_FN  + (size_t)MF_*D_*2;      // bf16 qn (MQ,768); reused as prep
static constexpr size_t OFF_OA  = OFF_QN  + (size_t)MQ_*D_*2;      // f32 off+attw (MQ,144)
static constexpr size_t OFF_WVT = OFF_OA  + (size_t)MQ_*144*4;     // bf16 W_val^T (768,768)
static constexpr size_t OFF_WOT = OFF_WVT + (size_t)D_*D_*2;       // bf16 W_out^T (768,768)
static constexpr size_t OFF_WCT = OFF_WOT + (size_t)D_*D_*2;       // bf16 Wcat^T (256,768)

__device__ __forceinline__ void async16(const void* g, void* l) {
  __builtin_amdgcn_global_load_lds((const __attribute__((address_space(1))) void*)g,
                                   (__attribute__((address_space(3))) void*)l, 16, 0, 0);
}

// fused weight prep: blocks 0..143 transpose W_val, 144..287 transpose W_out,
// 288..1055 build Wcat^T
__global__ __launch_bounds__(256) void k_weights(const float* __restrict__ Wv, const float* __restrict__ Wo,
                                                 const float* __restrict__ Woff, const float* __restrict__ Wat,
                                                 bf16* __restrict__ WvT, bf16* __restrict__ WoT,
                                                 bf16* __restrict__ WcT) {
  int bid = blockIdx.x;
  if (bid < 288) {
    const float* W = (bid < 144) ? Wv : Wo;
    bf16* WT = (bid < 144) ? WvT : WoT;
    int lb = (bid < 144) ? bid : bid - 144;
    __shared__ float t[64][65];
    int bx = lb % 12, by = lb / 12;
    int n0 = bx*64, k0 = by*64;
    int col = threadIdx.x & 63, rg = threadIdx.x >> 6;
    #pragma unroll
    for (int i=0;i<16;++i) { int row = i*4+rg; t[row][col] = W[(size_t)(k0+row)*D_ + n0+col]; }
    __syncthreads();
    #pragma unroll
    for (int i=0;i<16;++i) { int row = i*4+rg; WT[(size_t)(n0+row)*D_ + k0+col] = __float2bfloat16(t[col][row]); }
  } else {
    int idx = (bid-288)*256 + threadIdx.x;     // over 256*768, exact
    int j = idx / D_, k = idx - j*D_;
    float v = 0.f;
    if (j < 96)       v = Woff[(size_t)k*96 + j];
    else if (j < 144) v = Wat[(size_t)k*48 + (j-96)];
    WcT[idx] = __float2bfloat16(v);
  }
}

// wave-per-row LayerNorm: rows 0..16383 -> query rows, 16384..81919 -> feat.
__global__ __launch_bounds__(256) void k_ln(const float* __restrict__ query, const float* __restrict__ feat,
                                            const float* __restrict__ qw, const float* __restrict__ qb,
                                            const float* __restrict__ fw, const float* __restrict__ fb,
                                            bf16* __restrict__ qn, bf16* __restrict__ fn) {
  int r = blockIdx.x*4 + (threadIdx.x>>6);
  int lane = threadIdx.x & 63;
  const float* src; const float* w; const float* bia; bf16* dst;
  if (r < MQ_) {
    int bat = r >> 10, rr = r & 1023;
    src = query + ((size_t)bat*QR_ + TASK_ + rr)*D_;
    w = qw; bia = qb; dst = qn + (size_t)r*D_;
  } else {
    int fr = r - MQ_;
    src = feat + (size_t)fr*D_;
    w = fw; bia = fb; dst = fn + (size_t)fr*D_;
  }
  float4 v[3];
  #pragma unroll
  for (int j=0;j<3;++j) v[j] = ((const float4*)src)[lane + 64*j];
  float s = 0.f, s2 = 0.f;
  #pragma unroll
  for (int j=0;j<3;++j) {
    s  += v[j].x + v[j].y + v[j].z + v[j].w;
    s2 += v[j].x*v[j].x + v[j].y*v[j].y + v[j].z*v[j].z + v[j].w*v[j].w;
  }
  #pragma unroll
  for (int o=32;o>0;o>>=1){ s += __shfl_xor(s,o); s2 += __shfl_xor(s2,o); }
  float mu  = s*(1.f/D_);
  float var = s2*(1.f/D_) - mu*mu;
  float rstd = rsqrtf(var + 1e-6f);
  #pragma unroll
  for (int j=0;j<3;++j) {
    float4 ww = ((const float4*)w)[lane + 64*j];
    float4 bb = ((const float4*)bia)[lane + 64*j];
    short4v o4;
    o4[0] = (short)__bfloat16_as_ushort(__float2bfloat16((v[j].x-mu)*rstd*ww.x + bb.x));
    o4[1] = (short)__bfloat16_as_ushort(__float2bfloat16((v[j].y-mu)*rstd*ww.y + bb.y));
    o4[2] = (short)__bfloat16_as_ushort(__float2bfloat16((v[j].z-mu)*rstd*ww.z + bb.z));
    o4[3] = (short)__bfloat16_as_ushort(__float2bfloat16((v[j].w-mu)*rstd*ww.w + bb.w));
    *(short4v*)(dst + 4*(lane + 64*j)) = o4;
  }
}

// 256x256 tile, 8 waves (wave tile 128x64), BK=32, ring-3 LDS, 4-phase
// interleave with per-phase double-barrier lockstep (m201 template structure):
// {stage | ds_read -> barrier -> setprio MFMA setprio -> barrier}.
// One counted vmcnt per K-tile (never 0 in main loop).
__global__ __launch_bounds__(512, 2) void k_gemm_val(const bf16* __restrict__ A, const bf16* __restrict__ BT,
                                                     const float* __restrict__ bias0, bf16* __restrict__ outp) {
  __shared__ char lds[98304];    // 3 buffers x (A 16KB + B 16KB)
  const int K = D_;
  const int tid = threadIdx.x, wid = tid>>6, lane = tid&63;
  const int nwg = gridDim.x*gridDim.y;            // 768
  const int d = blockIdx.y*gridDim.x + blockIdx.x;
  const int logical = (d & 7)*(nwg>>3) + (d>>3);  // XCD-chunked
  const int bm = (logical/3)*256, bn = (logical%3)*256;
  const int wm = wid>>2, wn = wid&3;              // wave tile rows [wm*128,+128), cols [wn*64,+64)
  // staging: thread tid covers row tid>>2, 16B slot (tid&3), XOR-swizzled source
  const int srow = tid>>2;
  const int sslot = ((tid&3) ^ ((tid>>3)&3))*8;
  const bf16* gA0 = A  + (size_t)(bm + srow)*K + sslot;
  const bf16* gA1 = A  + (size_t)(bm + 128 + srow)*K + sslot;
  const bf16* gB0 = BT + (size_t)(bn + srow)*K + sslot;
  const bf16* gB1 = BT + (size_t)(bn + 128 + srow)*K + sslot;
  // wave-uniform LDS dest base; HW writes base + lane*16 -> byte tid*16 overall
  const int dstbase = (tid>>6)<<10;
  // read-side fragment offset (row lane&15, XOR'd 16B slot)
  const int rb = (lane&15)*64 + ((((lane>>4) ^ ((lane>>1)&3)))<<4);
  floatx4 acc[8][4] = {};
  auto stageAll = [&](int k0, char* buf) {
    async16(gA0+k0, buf + dstbase);
    async16(gA1+k0, buf + 8192 + dstbase);
    async16(gB0+k0, buf + 16384 + dstbase);
    async16(gB1+k0, buf + 24576 + dstbase);
  };
  stageAll(0,  lds);
  stageAll(32, lds + 32768);
  const int NT = K >> 5;     // 24
  int cur = 0, nxt = 2;
  for (int k = 0; k < NT; ++k) {
    if (k < NT-1) asm volatile("s_waitcnt vmcnt(4)" ::: "memory");
    else          asm volatile("s_waitcnt vmcnt(0)" ::: "memory");
    __builtin_amdgcn_s_barrier();          // buf[cur] fully staged; buf[nxt] free
    __builtin_amdgcn_sched_barrier(0);
    const int kk = (k+2)*32;
    const bool pf = (k+2 < NT);            // wave-uniform
    const char* lA = lds + cur*32768;
    const char* lB = lA + 16384;
    char* bufn = lds + nxt*32768;
    short8 af[8], bfr[4];
    // ---- phase 0: stage A-half0 | read A0-3,B0-1 | MFMA (mi0-3, ni0-1)
    if (pf) async16(gA0+kk, bufn + dstbase);
    #pragma unroll
    for (int i=0;i<4;++i) af[i] = *(const short8*)(lA + (wm*128 + i*16)*64 + rb);
    #pragma unroll
    for (int i=0;i<2;++i) bfr[i] = *(const short8*)(lB + (wn*64 + i*16)*64 + rb);
    __builtin_amdgcn_s_barrier();
    __builtin_amdgcn_s_setprio(1);
    #pragma unroll
    for (int mi=0;mi<4;++mi)
      #pragma unroll
      for (int ni=0;ni<2;++ni)
        acc[mi][ni] = __builtin_amdgcn_mfma_f32_16x16x32_bf16(af[mi], bfr[ni], acc[mi][ni], 0, 0, 0);
    __builtin_amdgcn_s_setprio(0);
    __builtin_amdgcn_s_barrier();
    __builtin_amdgcn_sched_barrier(0);
    // ---- phase 1: stage A-half1 | read B2-3 | MFMA (mi0-3, ni2-3)
    if (pf) async16(gA1+kk, bufn + 8192 + dstbase);
    #pragma unroll
    for (int i=2;i<4;++i) bfr[i] = *(const short8*)(lB + (wn*64 + i*16)*64 + rb);
    __builtin_amdgcn_s_barrier();
    __builtin_amdgcn_s_setprio(1);
    #pragma unroll
    for (int mi=0;mi<4;++mi)
      #pragma unroll
      for (int ni=2;ni<4;++ni)
        acc[mi][ni] = __builtin_amdgcn_mfma_f32_16x16x32_bf16(af[mi], bfr[ni], acc[mi][ni], 0, 0, 0);
    __builtin_amdgcn_s_setprio(0);
    __builtin_amdgcn_s_barrier();
    __builtin_amdgcn_sched_barrier(0);
    // ---- phase 2: stage B-half0 | read A4-7 | MFMA (mi4-7, ni0-1)
    if (pf) async16(gB0+kk, bufn + 16384 + dstbase);
    #pragma unroll
    for (int i=4;i<8;++i) af[i] = *(const short8*)(lA + (wm*128 + i*16)*64 + rb);
    __builtin_amdgcn_s_barrier();
    __builtin_amdgcn_s_setprio(1);
    #pragma unroll
    for (int mi=4;mi<8;++mi)
      #pragma unroll
      for (int ni=0;ni<2;++ni)
        acc[mi][ni] = __builtin_amdgcn_mfma_f32_16x16x32_bf16(af[mi], bfr[ni], acc[mi][ni], 0, 0, 0);
    __builtin_amdgcn_s_setprio(0);
    __builtin_amdgcn_s_barrier();
    __builtin_amdgcn_sched_barrier(0);
    // ---- phase 3: stage B-half1 | MFMA (mi4-7, ni2-3)
    if (pf) async16(gB1+kk, bufn + 24576 + dstbase);
    __builtin_amdgcn_s_barrier();
    __builtin_amdgcn_s_setprio(1);
    #pragma unroll
    for (int mi=4;mi<8;++mi)
      #pragma unroll
      for (int ni=2;ni<4;++ni)
        acc[mi][ni] = __builtin_amdgcn_mfma_f32_16x16x32_bf16(af[mi], bfr[ni], acc[mi][ni], 0, 0, 0);
    __builtin_amdgcn_s_setprio(0);
    __builtin_amdgcn_sched_barrier(0);
    cur = (cur==2) ? 0 : cur+1;
    nxt = (nxt==2) ? 0 : nxt+1;
  }
  // epilogue: scatter to (b, h, pix, hd) bf16
  const int rowb = (lane>>4)*4, col = lane&15;
  #pragma unroll
  for (int mi=0;mi<8;++mi) {
    #pragma unroll
    for (int ni=0;ni<4;++ni) {
      const int gn = bn + wn*64 + ni*16 + col;
      const float bv = bias0[gn];
      const int h = gn >> 6, hd = gn & 63;
      #pragma unroll
      for (int r=0;r<4;++r) {
        const int gm = bm + wm*128 + mi*16 + rowb + r;
        const int b = gm >> 12, pix = gm & 4095;
        outp[(((size_t)(b*HH_+h)*LIN_ + pix)<<6) + hd] = __float2bfloat16(acc[mi][ni][r] + bv);
      }
    }
  }
}

// 128x128 tile bf16 MFMA GEMM (proven round-4 structure) for MODE 1 / MODE 2.
template<int MODE>
__global__ __launch_bounds__(256) void k_gemm(const bf16* __restrict__ A, const bf16* __restrict__ BT,
                                              int K,
                                              const float* __restrict__ bias0, const float* __restrict__ bias1,
                                              void* __restrict__ outp,
                                              const float* __restrict__ query, const float* __restrict__ gamma) {
  __shared__ char lds[49152];    // 3 buffers x (A 8KB + B 8KB)
  const int tid = threadIdx.x, wid = tid>>6, lane = tid&63;
  const int nwg = gridDim.x*gridDim.y, ny = gridDim.y;
  const int d = blockIdx.y*gridDim.x + blockIdx.x;
  const int logical = (d & 7)*(nwg>>3) + (d>>3);
  const int bm = (logical/ny)*128, bn = (logical%ny)*128;
  const int wr = wid>>1, wc = wid&1;
  const int c0 = wid*2, c1 = c0+1;
  const int sr0 = c0*16 + (lane>>2), sr1 = sr0+16;
  const int skb = (((lane&3) ^ ((lane>>3)&3)))*8;
  const bf16* ga0 = A  + (size_t)(bm+sr0)*K + skb;
  const bf16* ga1 = A  + (size_t)(bm+sr1)*K + skb;
  const bf16* gb0 = BT + (size_t)(bn+sr0)*K + skb;
  const bf16* gb1 = BT + (size_t)(bn+sr1)*K + skb;
  const int rb = (lane&15)*64 + ((((lane>>4) ^ ((lane>>1)&3)))<<4);
  floatx4 acc[4][4] = {};
  auto stage = [&](int k0, char* buf) {
    char* dA = buf; char* dB = buf + 8192;
    async16(ga0+k0, dA + c0*1024); async16(ga1+k0, dA + c1*1024);
    async16(gb0+k0, dB + c0*1024); async16(gb1+k0, dB + c1*1024);
  };
  stage(0,  lds);
  stage(32, lds + 16384);
  const int NT = K >> 5;
  int cur = 0, nxt = 2;
  for (int k = 0; k < NT; ++k) {
    if (k < NT-1) asm volatile("s_waitcnt vmcnt(4)" ::: "memory");
    else          asm volatile("s_waitcnt vmcnt(0)" ::: "memory");
    __builtin_amdgcn_s_barrier();
    __builtin_amdgcn_sched_barrier(0);
    if (k + 2 < NT) stage((k+2)*32, lds + nxt*16384);
    const char* ldsA = lds + cur*16384; const char* ldsB = ldsA + 8192;
    short8 af[4], bfr[4];
    #pragma unroll
    for (int i=0;i<4;++i) {
      af[i]  = *(const short8*)(ldsA + (wr*64 + i*16)*64 + rb);
      bfr[i] = *(const short8*)(ldsB + (wc*64 + i*16)*64 + rb);
    }
    #pragma unroll
    for (int mi=0;mi<4;++mi)
      #pragma unroll
      for (int ni=0;ni<4;++ni)
        acc[mi][ni] = __builtin_amdgcn_mfma_f32_16x16x32_bf16(af[mi], bfr[ni], acc[mi][ni], 0, 0, 0);
    cur = (cur==2) ? 0 : cur+1;
    nxt = (nxt==2) ? 0 : nxt+1;
  }
  const int rowb = (lane>>4)*4, col = lane&15;
  #pragma unroll
  for (int mi=0;mi<4;++mi) {
    #pragma unroll
    for (int ni=0;ni<4;++ni) {
      const int gn = bn + wc*64 + ni*16 + col;
      #pragma unroll
      for (int r=0;r<4;++r) {
        const int gm = bm + wr*64 + mi*16 + rowb + r;
        float v = acc[mi][ni][r];
        if constexpr (MODE==1) {
          if (gn < 144) {
            v += (gn < 96) ? bias0[gn] : bias1[gn-96];
            ((float*)outp)[(size_t)gm*144 + gn] = v;
          }
        } else {
          v += bias0[gn];
          int b = gm >> 10, lq = gm & 1023;
          size_t idx = ((size_t)b*QR_ + TASK_ + lq)*D_ + gn;
          ((float*)outp)[idx] = query[idx] + gamma[gn]*v;
        }
      }
    }
  }
}

// precompute per (m,h,p): 4 corners x {combined weight, clamped pixel index};
// blocks 0..959 additionally copy the task-token rows to d_out
__global__ __launch_bounds__(256) void k_prep(const float* __restrict__ oa_all,
                                              const float* __restrict__ refp,
                                              float2* __restrict__ prep,
                                              const float* __restrict__ query, float* __restrict__ out) {
  int idx = blockIdx.x*256 + threadIdx.x;     // MQ_*HH_*4 = 786432, exact
  int p = idx & 3, mh = idx >> 2;
  int h = mh % HH_, m = mh / HH_;
  const float* oa = oa_all + (size_t)m*144;
  float l0 = oa[96+h*4+0], l1 = oa[96+h*4+1], l2 = oa[96+h*4+2], l3 = oa[96+h*4+3];
  float mx = fmaxf(fmaxf(l0,l1), fmaxf(l2,l3));
  float e0 = expf(l0-mx), e1 = expf(l1-mx), e2 = expf(l2-mx), e3 = expf(l3-mx);
  float inv = 1.f/(e0+e1+e2+e3);
  float ep = (p==0)?e0:(p==1)?e1:(p==2)?e2:e3;
  float awp = ep*inv;
  float x = refp[(size_t)m*2+0]*64.f - 0.5f + oa[h*8+p*2+0];
  float y = refp[(size_t)m*2+1]*64.f - 0.5f + oa[h*8+p*2+1];
  float x0f = floorf(x), y0f = floorf(y);
  int ix = (int)x0f, iy = (int)y0f;
  float fx = x-x0f, fy = y-y0f;
  float wx[2] = {1.f-fx, fx}, wy[2] = {1.f-fy, fy};
  float2 e[4];
  #pragma unroll
  for (int c=0;c<4;++c) {
    int dx = c&1, dy = c>>1;
    int xc = ix+dx, yc = iy+dy;
    bool valid = ((unsigned)xc < 64u) && ((unsigned)yc < 64u);
    float w = valid ? awp*wx[dx]*wy[dy] : 0.f;
    int xi = min(max(xc,0),63), yi = min(max(yc,0),63);
    e[c].x = w;
    e[c].y = __int_as_float(yi*64+xi);
  }
  float2* dst = prep + (size_t)mh*16 + p*4;
  *(float4*)(dst)   = make_float4(e[0].x, e[0].y, e[1].x, e[1].y);
  *(float4*)(dst+2) = make_float4(e[2].x, e[2].y, e[3].x, e[3].y);
  // task-token passthrough: B_*TASK_*D_/4 = 245760 float4 -> 960 blocks
  if (blockIdx.x < 960) {
    int ci = blockIdx.x*256 + threadIdx.x;
    const int perb = TASK_*D_/4;               // 15360 float4 per batch
    int b = ci / perb, r = ci - b*perb;
    const float4* s = (const float4*)(query + (size_t)b*QR_*D_) + r;
    float4* dd = (float4*)(out + (size_t)b*QR_*D_) + r;
    *dd = *s;
  }
}

// gather+combine: 32-lane group = one (m,h); lane = (channel_octet<<2)|point.
// Each lane loads short8 (8 channels, 16B) per corner; quad shfl_xor reduce.
__global__ __launch_bounds__(256) void k_sample(const float2* __restrict__ prep,
                                                const bf16* __restrict__ value,
                                                bf16* __restrict__ sampout) {
  int g  = blockIdx.x*8 + (threadIdx.x>>5);   // (b*1024+q)*12 + h
  int l  = threadIdx.x & 31;
  int c8 = l >> 2, p = l & 3;
  int h = g % HH_, m = g / HH_;
  int b = m >> 10;
  const float2* pb = prep + (size_t)g*16 + p*4;
  float4 e01 = *(const float4*)(pb);
  float4 e23 = *(const float4*)(pb+2);
  const bf16* vb = value + (((size_t)(b*HH_+h))<<18) + (c8<<3);   // LIN_*HD_ = 262144
  float a[8] = {};
  float wv[4]  = {e01.x, e01.z, e23.x, e23.z};
  int   pix[4] = {__float_as_int(e01.y), __float_as_int(e01.w),
                  __float_as_int(e23.y), __float_as_int(e23.w)};
  #pragma unroll
  for (int c=0;c<4;++c) {
    short8 v = *(const short8*)(vb + ((size_t)pix[c]<<6));
    float w = wv[c];
    #pragma unroll
    for (int j=0;j<8;++j)
      a[j] += w*__uint_as_float(((unsigned)(unsigned short)v[j])<<16);
  }
  #pragma unroll
  for (int j=0;j<8;++j) { a[j] += __shfl_xor(a[j],1); a[j] += __shfl_xor(a[j],2); }
  if (p == 0) {
    short8 o;
    #pragma unroll
    for (int j=0;j<8;++j)
      o[j] = (short)__bfloat16_as_ushort(__float2bfloat16(a[j]));
    *(short8*)(sampout + (size_t)m*D_ + h*64 + c8*8) = o;
  }
}

extern "C" void kernel_launch(void* const* d_in, const int* in_sizes, int n_in,
                              void* d_out, int out_size, void* d_ws, size_t ws_size,
                              hipStream_t stream) {
  (void)in_sizes; (void)n_in; (void)out_size; (void)ws_size;
  const float* query = (const float*)d_in[0];
  const float* refp  = (const float*)d_in[1];
  const float* feat  = (const float*)d_in[2];
  const float* qn_w  = (const float*)d_in[5];
  const float* qn_b  = (const float*)d_in[6];
  const float* fn_w  = (const float*)d_in[7];
  const float* fn_b  = (const float*)d_in[8];
  const float* gamma = (const float*)d_in[9];
  const float* W_off = (const float*)d_in[10];
  const float* b_off = (const float*)d_in[11];
  const float* W_attw= (const float*)d_in[12];
  const float* b_attw= (const float*)d_in[13];
  const float* W_val = (const float*)d_in[14];
  const float* b_val = (const float*)d_in[15];
  const float* W_out = (const float*)d_in[16];
  const float* b_out = (const float*)d_in[17];
  char*  ws  = (char*)d_ws;
  float* out = (float*)d_out;

  bf16*   wsVal  = (bf16*)(ws + OFF_VAL);
  bf16*   wsFn   = (bf16*)(ws + OFF_FN);
  bf16*   wsQn   = (bf16*)(ws + OFF_QN);
  float*  wsOA   = (float*)(ws + OFF_OA);
  bf16*   wsWvT  = (bf16*)(ws + OFF_WVT);
  bf16*   wsWoT  = (bf16*)(ws + OFF_WOT);
  bf16*   wsWcT  = (bf16*)(ws + OFF_WCT);
  float2* wsPrep = (float2*)(ws + OFF_QN);   // qn dead after MODE-1 GEMM
  bf16*   wsSamp = wsFn;                     // fn dead after value GEMM

  k_weights<<<1056, 256, 0, stream>>>(W_val, W_out, W_off, W_attw, wsWvT, wsWoT, wsWcT);
  k_ln<<<(MQ_+MF_)/4, 256, 0, stream>>>(query, feat, qn_w, qn_b, fn_w, fn_b, wsQn, wsFn);
  k_gemm<1><<<dim3(MQ_/128, 2), 256, 0, stream>>>(wsQn, wsWcT, D_, b_off, b_attw, wsOA, nullptr, nullptr);
  k_prep<<<(MQ_*HH_*4)/256, 256, 0, stream>>>(wsOA, refp, wsPrep, query, out);
  k_gemm_val<<<dim3(MF_/256, 3), 512, 0, stream>>>(wsFn, wsWvT, b_val, wsVal);
  k_sample<<<(MQ_*HH_)/8, 256, 0, stream>>>(wsPrep, wsVal, wsSamp);
  k_gemm<2><<<dim3(MQ_/128, 6), 256, 0, stream>>>(wsSamp, wsWoT, D_, b_out, nullptr, out, query, gamma);
}